// Round 1
// baseline (2898.735 us; speedup 1.0000x reference)
//
#include <hip/hip_runtime.h>
#include <hip/hip_bf16.h>

// Problem constants
#define BT    16384      // B*T
#define NVAR  16
#define DDIM  64
#define FDIM  1024       // N*D
#define HDIM  256
#define ODIM  256
#define CDIM  64
#define TLEN  256

// ---------------------------------------------------------------------------
// Generic f32 tiled GEMM: C[M,N] = act(A[M,K] @ B[K,N] + bias + rowAdd)
// 64x64 block tile, 256 threads, 4x4 per thread, K-tile 16.
// M = gridDim.y*64, N = gridDim.x*64 (all dims multiples required).
// rowAdd (optional): adds rowAdd[(row>>8)*ldc + col]   (ctx hidden for K1)
// act: 0 = none, 1 = elu
// ---------------------------------------------------------------------------
__global__ __launch_bounds__(256)
void gemm_f32(const float* __restrict__ A, const float* __restrict__ B,
              const float* __restrict__ bias, float* __restrict__ C,
              int K, int lda, int ldb, int ldc,
              const float* __restrict__ rowAdd, int act)
{
    __shared__ float As[16][68];
    __shared__ float Bs[16][68];
    int tid  = threadIdx.x;
    long brow = (long)blockIdx.y * 64;
    int  bcol = blockIdx.x * 64;
    int tr = tid >> 4, tc = tid & 15;           // compute tile coords
    int lrow = tid >> 2, lk = (tid & 3) << 2;   // A-load coords
    int bk = tid >> 4,  bc = (tid & 15) << 2;   // B-load coords

    const float* Ap = A + (brow + lrow) * (long)lda + lk;
    const float* Bp = B + (long)bk * ldb + bcol + bc;

    float acc[4][4] = {};
    for (int k0 = 0; k0 < K; k0 += 16) {
        float4 av = *(const float4*)(Ap + k0);
        float4 bv = *(const float4*)(Bp + (long)k0 * ldb);
        __syncthreads();
        As[lk + 0][lrow] = av.x;
        As[lk + 1][lrow] = av.y;
        As[lk + 2][lrow] = av.z;
        As[lk + 3][lrow] = av.w;
        *(float4*)&Bs[bk][bc] = bv;
        __syncthreads();
#pragma unroll
        for (int kk = 0; kk < 16; ++kk) {
            float4 a4 = *(const float4*)&As[kk][tr << 2];
            float4 b4 = *(const float4*)&Bs[kk][tc << 2];
            float ar[4] = {a4.x, a4.y, a4.z, a4.w};
            float br[4] = {b4.x, b4.y, b4.z, b4.w};
#pragma unroll
            for (int i = 0; i < 4; ++i)
#pragma unroll
                for (int j = 0; j < 4; ++j)
                    acc[i][j] = fmaf(ar[i], br[j], acc[i][j]);
        }
    }
#pragma unroll
    for (int i = 0; i < 4; ++i) {
        long row = brow + (tr << 2) + i;
#pragma unroll
        for (int j = 0; j < 4; ++j) {
            int col = bcol + (tc << 2) + j;
            float v = acc[i][j];
            if (bias)   v += bias[col];
            if (rowAdd) v += rowAdd[(row >> 8) * (long)ldc + col];
            if (act)    v = v > 0.f ? v : (__expf(v) - 1.f);
            C[row * (long)ldc + col] = v;
        }
    }
}

// ---------------------------------------------------------------------------
// K2: flatten-GRN tail: skip(K=1024,16) + h2(K=256,16) + gate(16->32) + LN(16)
// + softmax(16) -> w.  One wave (64 threads) per row.
// ---------------------------------------------------------------------------
__global__ __launch_bounds__(64)
void k2_logits(const float* __restrict__ flat, const float* __restrict__ h1,
               const float* __restrict__ skipW, const float* __restrict__ skipb,
               const float* __restrict__ W2, const float* __restrict__ b2,
               const float* __restrict__ Wg, const float* __restrict__ bg,
               const float* __restrict__ gamma, const float* __restrict__ beta,
               float* __restrict__ wout)
{
    long row = blockIdx.x;
    int l = threadIdx.x;
    int c = l & 15, chunk = l >> 4;

    // skip = flat @ skipW + skipb   (K = 1024, split over 4 chunks of 256)
    const float* fr = flat + row * FDIM;
    float s = 0.f;
    int kbeg = chunk * 256;
#pragma unroll 4
    for (int k = kbeg; k < kbeg + 256; ++k)
        s = fmaf(fr[k], skipW[k * 16 + c], s);
    s += __shfl_xor(s, 16);
    s += __shfl_xor(s, 32);
    float skip = s + skipb[c];

    // h2 = h1row @ W2 + b2  (K = 256)
    const float* hr = h1 + row * HDIM;
    float t = 0.f;
    int kb2 = chunk * 64;
#pragma unroll 4
    for (int k = kb2; k < kb2 + 64; ++k)
        t = fmaf(hr[k], W2[k * 16 + c], t);
    t += __shfl_xor(t, 16);
    t += __shfl_xor(t, 32);
    float h2 = t + b2[c];   // lane j (j<16) holds h2[j]

    // g = h2 @ Wg + bg  (16 -> 32); lane l computes g[l & 31]
    int cc = l & 31;
    float gval = bg[cc];
#pragma unroll
    for (int j = 0; j < 16; ++j)
        gval = fmaf(__shfl(h2, j), Wg[j * 32 + cc], gval);

    float a2    = __shfl(gval, c);
    float gate2 = __shfl(gval, c + 16);
    float sv = skip + a2 * (1.f / (1.f + __expf(-gate2)));

    // LN over the 16 columns (xor-reduce within 16-lane groups)
    float sum = sv, sq = sv * sv;
#pragma unroll
    for (int m = 1; m < 16; m <<= 1) {
        sum += __shfl_xor(sum, m);
        sq  += __shfl_xor(sq, m);
    }
    float mean = sum * (1.f / 16.f);
    float var  = sq * (1.f / 16.f) - mean * mean;
    float logit = (sv - mean) * rsqrtf(var + 1e-5f) * gamma[c] + beta[c];

    // softmax over 16
    float mx = logit;
#pragma unroll
    for (int m = 1; m < 16; m <<= 1) mx = fmaxf(mx, __shfl_xor(mx, m));
    float e = __expf(logit - mx);
    float es = e;
#pragma unroll
    for (int m = 1; m < 16; m <<= 1) es += __shfl_xor(es, m);
    float w = e / es;
    if (l < 16) wout[row * NVAR + l] = w;
}

// ---------------------------------------------------------------------------
// Per-variable combine: pv = LN(skip + a*sig(gate)); sel (+)= pv * w[:,n]
// One block (256 threads) per row.
// ---------------------------------------------------------------------------
__global__ __launch_bounds__(256)
void combine_sel(const float* __restrict__ skipb, const float* __restrict__ gbuf,
                 const float* __restrict__ gamma, const float* __restrict__ beta,
                 const float* __restrict__ wsm, float* __restrict__ sel, int n)
{
    __shared__ float red[8];
    long row = blockIdx.x;
    int c = threadIdx.x;
    float a = gbuf[row * 512 + c];
    float g = gbuf[row * 512 + 256 + c];
    float s = skipb[row * 256 + c] + a * (1.f / (1.f + __expf(-g)));

    float sum = s, sq = s * s;
#pragma unroll
    for (int m = 1; m < 64; m <<= 1) {
        sum += __shfl_xor(sum, m);
        sq  += __shfl_xor(sq, m);
    }
    int wid = c >> 6, lane = c & 63;
    if (lane == 0) { red[wid] = sum; red[4 + wid] = sq; }
    __syncthreads();
    sum = red[0] + red[1] + red[2] + red[3];
    sq  = red[4] + red[5] + red[6] + red[7];
    float mean = sum * (1.f / 256.f);
    float var  = sq * (1.f / 256.f) - mean * mean;
    float pv = (s - mean) * rsqrtf(var + 1e-5f) * gamma[n * 256 + c] + beta[n * 256 + c];
    float wv = wsm[row * NVAR + n];
    long idx = row * 256 + c;
    float prev = (n == 0) ? 0.f : sel[idx];
    sel[idx] = prev + pv * wv;
}

// ---------------------------------------------------------------------------
// K5: output GRN, fused per 8-row block (weights streamed once per block).
// ---------------------------------------------------------------------------
#define R5 8
__global__ __launch_bounds__(256)
void k5_out(const float* __restrict__ sel,
            const float* __restrict__ W1, const float* __restrict__ b1,
            const float* __restrict__ W2, const float* __restrict__ b2,
            const float* __restrict__ Wg, const float* __restrict__ bg,
            const float* __restrict__ gamma, const float* __restrict__ beta,
            float* __restrict__ out)
{
    __shared__ float ss[R5][256];
    __shared__ float hs[R5][256];
    __shared__ float h2s[R5][256];
    __shared__ float red[8];
    int c = threadIdx.x;
    long row0 = (long)blockIdx.x * R5;

#pragma unroll
    for (int r = 0; r < R5; ++r) ss[r][c] = sel[(row0 + r) * 256 + c];
    __syncthreads();

    float acc[R5];
#pragma unroll
    for (int r = 0; r < R5; ++r) acc[r] = b1[c];
    for (int k = 0; k < 256; ++k) {
        float wv = W1[k * 256 + c];
#pragma unroll
        for (int r = 0; r < R5; ++r) acc[r] = fmaf(ss[r][k], wv, acc[r]);
    }
#pragma unroll
    for (int r = 0; r < R5; ++r) {
        float v = acc[r];
        hs[r][c] = v > 0.f ? v : (__expf(v) - 1.f);
    }
    __syncthreads();

#pragma unroll
    for (int r = 0; r < R5; ++r) acc[r] = b2[c];
    for (int k = 0; k < 256; ++k) {
        float wv = W2[k * 256 + c];
#pragma unroll
        for (int r = 0; r < R5; ++r) acc[r] = fmaf(hs[r][k], wv, acc[r]);
    }
#pragma unroll
    for (int r = 0; r < R5; ++r) h2s[r][c] = acc[r];
    __syncthreads();

    float aacc[R5], gacc[R5];
#pragma unroll
    for (int r = 0; r < R5; ++r) { aacc[r] = bg[c]; gacc[r] = bg[256 + c]; }
    for (int k = 0; k < 256; ++k) {
        float wa = Wg[k * 512 + c];
        float wg2 = Wg[k * 512 + 256 + c];
#pragma unroll
        for (int r = 0; r < R5; ++r) {
            aacc[r] = fmaf(h2s[r][k], wa, aacc[r]);
            gacc[r] = fmaf(h2s[r][k], wg2, gacc[r]);
        }
    }

    int wid = c >> 6, lane = c & 63;
    for (int r = 0; r < R5; ++r) {
        float s = ss[r][c] + aacc[r] * (1.f / (1.f + __expf(-gacc[r])));
        float sum = s, sq = s * s;
#pragma unroll
        for (int m = 1; m < 64; m <<= 1) {
            sum += __shfl_xor(sum, m);
            sq  += __shfl_xor(sq, m);
        }
        __syncthreads();
        if (lane == 0) { red[wid] = sum; red[4 + wid] = sq; }
        __syncthreads();
        sum = red[0] + red[1] + red[2] + red[3];
        sq  = red[4] + red[5] + red[6] + red[7];
        float mean = sum * (1.f / 256.f);
        float var  = sq * (1.f / 256.f) - mean * mean;
        out[(row0 + r) * 256 + c] = (s - mean) * rsqrtf(var + 1e-5f) * gamma[c] + beta[c];
    }
}

// ---------------------------------------------------------------------------
extern "C" void kernel_launch(void* const* d_in, const int* in_sizes, int n_in,
                              void* d_out, int out_size, void* d_ws, size_t ws_size,
                              hipStream_t stream)
{
    const float* vars     = (const float*)d_in[0];
    const float* ctx      = (const float*)d_in[1];
    const float* fg_W1    = (const float*)d_in[2];
    const float* fg_b1    = (const float*)d_in[3];
    const float* fg_Wc    = (const float*)d_in[4];
    const float* fg_W2    = (const float*)d_in[5];
    const float* fg_b2    = (const float*)d_in[6];
    const float* fg_Wg    = (const float*)d_in[7];
    const float* fg_bg    = (const float*)d_in[8];
    const float* fg_skipW = (const float*)d_in[9];
    const float* fg_skipb = (const float*)d_in[10];
    const float* fg_gamma = (const float*)d_in[11];
    const float* fg_beta  = (const float*)d_in[12];
    const float* vg_W1    = (const float*)d_in[13];
    const float* vg_b1    = (const float*)d_in[14];
    const float* vg_W2    = (const float*)d_in[15];
    const float* vg_b2    = (const float*)d_in[16];
    const float* vg_Wg    = (const float*)d_in[17];
    const float* vg_bg    = (const float*)d_in[18];
    const float* vg_skipW = (const float*)d_in[19];
    const float* vg_skipb = (const float*)d_in[20];
    const float* vg_gamma = (const float*)d_in[21];
    const float* vg_beta  = (const float*)d_in[22];
    const float* og_W1    = (const float*)d_in[23];
    const float* og_b1    = (const float*)d_in[24];
    const float* og_W2    = (const float*)d_in[25];
    const float* og_b2    = (const float*)d_in[26];
    const float* og_Wg    = (const float*)d_in[27];
    const float* og_bg    = (const float*)d_in[28];
    const float* og_gamma = (const float*)d_in[29];
    const float* og_beta  = (const float*)d_in[30];

    float* out = (float*)d_out;
    float* wsm = out + (long)BT * ODIM;       // softmax weights output [BT,16]

    // Workspace layout (floats). gb overlays slotA+slotB (h1 / hb are dead by then);
    // skipb overlays slotC (h2b dead after the Wg GEMM).
    float* ws    = (float*)d_ws;
    float* slotA = ws;                         // h1 [BT,256]  -> gb lower half
    float* slotB = ws + 4194304;               // hb [BT,256]  -> gb upper half
    float* slotC = ws + 8388608;               // h2b [BT,256] -> skipb
    float* sel   = ws + 12582912;              // sel [BT,256]
    float* ctxh  = ws + 16777216;              // ctxh [64,256]
    float* gb    = slotA;                      // [BT,512] contiguous over A+B

    dim3 blk(256);

    // K0: ctxh = context @ fg_Wc     [64,64]@[64,256]
    gemm_f32<<<dim3(4, 1), blk, 0, stream>>>(ctx, fg_Wc, nullptr, ctxh,
                                             64, CDIM, HDIM, HDIM, nullptr, 0);
    // K1: h1 = elu(flat @ fg_W1 + b1 + ctxh[b])
    gemm_f32<<<dim3(4, 256), blk, 0, stream>>>(vars, fg_W1, fg_b1, slotA,
                                               FDIM, FDIM, HDIM, HDIM, ctxh, 1);
    // K2: logits + softmax -> w
    k2_logits<<<BT, 64, 0, stream>>>(vars, slotA, fg_skipW, fg_skipb,
                                     fg_W2, fg_b2, fg_Wg, fg_bg,
                                     fg_gamma, fg_beta, wsm);

    // Per-variable GRNs
    for (int n = 0; n < NVAR; ++n) {
        // hb = elu(x_n @ W1_n + b1_n)          K=64
        gemm_f32<<<dim3(4, 256), blk, 0, stream>>>(vars + n * DDIM, vg_W1 + n * DDIM * HDIM,
                                                   vg_b1 + n * HDIM, slotB,
                                                   DDIM, FDIM, HDIM, HDIM, nullptr, 1);
        // h2b = hb @ W2_n + b2_n               K=256
        gemm_f32<<<dim3(4, 256), blk, 0, stream>>>(slotB, vg_W2 + n * HDIM * ODIM,
                                                   vg_b2 + n * ODIM, slotC,
                                                   HDIM, HDIM, ODIM, ODIM, nullptr, 0);
        // gb = h2b @ Wg_n + bg_n               K=256, N=512
        gemm_f32<<<dim3(8, 256), blk, 0, stream>>>(slotC, vg_Wg + n * ODIM * 512,
                                                   vg_bg + n * 512, gb,
                                                   ODIM, ODIM, 512, 512, nullptr, 0);
        // skipb = x_n @ skipW_n + skipb_n      K=64 (overwrites h2b)
        gemm_f32<<<dim3(4, 256), blk, 0, stream>>>(vars + n * DDIM, vg_skipW + n * DDIM * ODIM,
                                                   vg_skipb + n * ODIM, slotC,
                                                   DDIM, FDIM, ODIM, ODIM, nullptr, 0);
        // sel (+)= LN(skip + a*sig(gate)) * w[:,n]
        combine_sel<<<BT, 256, 0, stream>>>(slotC, gb, vg_gamma, vg_beta, wsm, sel, n);
    }

    // K5: output GRN
    k5_out<<<BT / R5, 256, 0, stream>>>(sel, og_W1, og_b1, og_W2, og_b2,
                                        og_Wg, og_bg, og_gamma, og_beta, out);
}

// Round 2
// 1229.147 us; speedup vs baseline: 2.3583x; 2.3583x over previous
//
#include <hip/hip_runtime.h>
#include <hip/hip_bf16.h>

#define BT    16384
#define NVAR  16
#define DDIM  64
#define FDIM  1024
#define HDIM  256
#define ODIM  256
#define CDIM  64

typedef __bf16 bf16x8 __attribute__((ext_vector_type(8)));
typedef __bf16 bf16x4 __attribute__((ext_vector_type(4)));
typedef float  f32x4  __attribute__((ext_vector_type(4)));

__device__ __forceinline__ void gload16(const void* g, void* l) {
    __builtin_amdgcn_global_load_lds((const __attribute__((address_space(1))) void*)g,
                                     (__attribute__((address_space(3))) void*)l, 16, 0, 0);
}

// ---------------------------------------------------------------------------
// bf16 MFMA GEMM: C[M,N] = act(A[M,K] @ Bt[N,K]^T + bias)
// 128x128 tile, BK=64, 256 threads (4 waves, 2x2 of 64x64), 16x16x32 MFMA.
// LDS: A-tile [128][64] bf16 + B-tile [128][64] bf16, XOR-swizzled chunks.
// M = gridDim.y*128 rows, N = gridDim.x*128 cols, K % 64 == 0.
// ---------------------------------------------------------------------------
__global__ __launch_bounds__(256)
void gemm_bf16(const __bf16* __restrict__ A, const __bf16* __restrict__ Bt,
               const float* __restrict__ bias, __bf16* __restrict__ C,
               int K, int lda, int ldb, int ldc, int act)
{
    __shared__ char smem[32768];
    char* As = smem;
    char* Bs = smem + 16384;

    const int tid  = threadIdx.x;
    const int wid  = tid >> 6, lane = tid & 63;
    const int wr   = wid >> 1, wc = wid & 1;
    const int lr   = lane & 15, lc = lane >> 4;
    const long row0 = (long)blockIdx.y * 128;
    const int  col0 = blockIdx.x * 128;

    // per-thread staging coords (4 chunk-slots of 256 chunks each per tile)
    int ldsbase = (tid & ~63) << 4;          // wave-uniform chunk base * 16B

    f32x4 acc[4][4] = {};

    int rA[4], rB[4];
#pragma unroll
    for (int i = 0; i < 4; ++i) { rA[i] = wr * 64 + i * 16 + lr; rB[i] = wc * 64 + i * 16 + lr; }

    const int nk = K >> 6;
    for (int kt = 0; kt < nk; ++kt) {
        const int k0 = kt << 6;
        __syncthreads();
#pragma unroll
        for (int s = 0; s < 4; ++s) {
            int q  = s * 256 + tid;
            int r  = q >> 3, cs = q & 7;
            int cg = cs ^ (r & 7);
            gload16(A  + (row0 + r) * (long)lda + k0 + (cg << 3), As + (s << 12) + ldsbase);
            gload16(Bt + (long)(col0 + r) * ldb + k0 + (cg << 3), Bs + (s << 12) + ldsbase);
        }
        __syncthreads();
#pragma unroll
        for (int ks = 0; ks < 2; ++ks) {
            bf16x8 af[4], bf[4];
#pragma unroll
            for (int i = 0; i < 4; ++i) {
                int c = ks * 4 + lc;
                af[i] = *(const bf16x8*)(As + rA[i] * 128 + (((c ^ (rA[i] & 7))) << 4));
                bf[i] = *(const bf16x8*)(Bs + rB[i] * 128 + (((c ^ (rB[i] & 7))) << 4));
            }
#pragma unroll
            for (int i = 0; i < 4; ++i)
#pragma unroll
                for (int j = 0; j < 4; ++j)
                    acc[i][j] = __builtin_amdgcn_mfma_f32_16x16x32_bf16(af[i], bf[j], acc[i][j], 0, 0, 0);
        }
    }

    // epilogue: C/D layout col=lane&15, row=(lane>>4)*4+reg
#pragma unroll
    for (int j = 0; j < 4; ++j) {
        int col = col0 + wc * 64 + j * 16 + lr;
        float bv = bias ? bias[col] : 0.f;
#pragma unroll
        for (int i = 0; i < 4; ++i) {
            f32x4 v = acc[i][j];
#pragma unroll
            for (int q = 0; q < 4; ++q) {
                long row = row0 + wr * 64 + i * 16 + lc * 4 + q;
                float x = v[q] + bv;
                if (act) x = x > 0.f ? x : (__expf(x) - 1.f);
                C[row * (long)ldc + col] = (__bf16)x;
            }
        }
    }
}

// ---------------------------------------------------------------------------
// Repack vg weights: [K][N] f32 -> [N][K] bf16, all 4 types x 16 vars, 1 launch
// ---------------------------------------------------------------------------
__global__ __launch_bounds__(256)
void repack_w(const float* __restrict__ W1, const float* __restrict__ W2,
              const float* __restrict__ Wg, const float* __restrict__ Sk,
              __bf16* __restrict__ tW1, __bf16* __restrict__ tW2,
              __bf16* __restrict__ tWg, __bf16* __restrict__ tSk)
{
    int type = blockIdx.z, n = blockIdx.y;
    int K, N; const float* in; __bf16* out;
    if (type == 0)      { K = 64;  N = 256; in = W1 + n * 64 * 256;  out = tW1 + n * 256 * 64; }
    else if (type == 1) { K = 256; N = 256; in = W2 + n * 256 * 256; out = tW2 + n * 256 * 256; }
    else if (type == 2) { K = 256; N = 512; in = Wg + n * 256 * 512; out = tWg + n * 512 * 256; }
    else                { K = 64;  N = 256; in = Sk + n * 64 * 256;  out = tSk + n * 256 * 64; }
    int tilesN = N >> 5;
    int tiles  = (K >> 5) * tilesN;
    if ((int)blockIdx.x >= tiles) return;
    int tk = blockIdx.x / tilesN, tn = blockIdx.x % tilesN;

    __shared__ float t[32][33];
    int tid = threadIdx.x;
    int r = tid >> 3, c0 = (tid & 7) << 2;
    float4 v = *(const float4*)(in + (size_t)(tk * 32 + r) * N + tn * 32 + c0);
    t[r][c0] = v.x; t[r][c0 + 1] = v.y; t[r][c0 + 2] = v.z; t[r][c0 + 3] = v.w;
    __syncthreads();
    int nn = tid >> 3, k4 = (tid & 7) << 2;
    bf16x4 o;
    o[0] = (__bf16)t[k4 + 0][nn]; o[1] = (__bf16)t[k4 + 1][nn];
    o[2] = (__bf16)t[k4 + 2][nn]; o[3] = (__bf16)t[k4 + 3][nn];
    *(bf16x4*)(out + (size_t)(tn * 32 + nn) * K + tk * 32 + k4) = o;
}

// Convert x_n slice [BT,64] f32 -> bf16
__global__ __launch_bounds__(256)
void conv_x(const float* __restrict__ vars, __bf16* __restrict__ xb, int n)
{
    int idx = blockIdx.x * 256 + threadIdx.x;       // 262144 total
    int row = idx >> 4, c4 = (idx & 15) << 2;
    float4 v = *(const float4*)(vars + (size_t)row * FDIM + n * DDIM + c4);
    bf16x4 o; o[0] = (__bf16)v.x; o[1] = (__bf16)v.y; o[2] = (__bf16)v.z; o[3] = (__bf16)v.w;
    *(bf16x4*)(xb + (size_t)row * DDIM + c4) = o;
}

// ---------------------------------------------------------------------------
// f32 tiled GEMM (kept for K0/K1)
// ---------------------------------------------------------------------------
__global__ __launch_bounds__(256)
void gemm_f32(const float* __restrict__ A, const float* __restrict__ B,
              const float* __restrict__ bias, float* __restrict__ C,
              int K, int lda, int ldb, int ldc,
              const float* __restrict__ rowAdd, int act)
{
    __shared__ float As[16][68];
    __shared__ float Bs[16][68];
    int tid  = threadIdx.x;
    long brow = (long)blockIdx.y * 64;
    int  bcol = blockIdx.x * 64;
    int tr = tid >> 4, tc = tid & 15;
    int lrow = tid >> 2, lk = (tid & 3) << 2;
    int bk = tid >> 4,  bc = (tid & 15) << 2;

    const float* Ap = A + (brow + lrow) * (long)lda + lk;
    const float* Bp = B + (long)bk * ldb + bcol + bc;

    float acc[4][4] = {};
    for (int k0 = 0; k0 < K; k0 += 16) {
        float4 av = *(const float4*)(Ap + k0);
        float4 bv = *(const float4*)(Bp + (long)k0 * ldb);
        __syncthreads();
        As[lk + 0][lrow] = av.x;
        As[lk + 1][lrow] = av.y;
        As[lk + 2][lrow] = av.z;
        As[lk + 3][lrow] = av.w;
        *(float4*)&Bs[bk][bc] = bv;
        __syncthreads();
#pragma unroll
        for (int kk = 0; kk < 16; ++kk) {
            float4 a4 = *(const float4*)&As[kk][tr << 2];
            float4 b4 = *(const float4*)&Bs[kk][tc << 2];
            float ar[4] = {a4.x, a4.y, a4.z, a4.w};
            float br[4] = {b4.x, b4.y, b4.z, b4.w};
#pragma unroll
            for (int i = 0; i < 4; ++i)
#pragma unroll
                for (int j = 0; j < 4; ++j)
                    acc[i][j] = fmaf(ar[i], br[j], acc[i][j]);
        }
    }
#pragma unroll
    for (int i = 0; i < 4; ++i) {
        long row = brow + (tr << 2) + i;
#pragma unroll
        for (int j = 0; j < 4; ++j) {
            int col = bcol + (tc << 2) + j;
            float v = acc[i][j];
            if (bias)   v += bias[col];
            if (rowAdd) v += rowAdd[(row >> 8) * (long)ldc + col];
            if (act)    v = v > 0.f ? v : (__expf(v) - 1.f);
            C[row * (long)ldc + col] = v;
        }
    }
}

// ---------------------------------------------------------------------------
// K2: flatten-GRN tail + softmax -> w. One wave per row.
// ---------------------------------------------------------------------------
__global__ __launch_bounds__(64)
void k2_logits(const float* __restrict__ flat, const float* __restrict__ h1,
               const float* __restrict__ skipW, const float* __restrict__ skipb,
               const float* __restrict__ W2, const float* __restrict__ b2,
               const float* __restrict__ Wg, const float* __restrict__ bg,
               const float* __restrict__ gamma, const float* __restrict__ beta,
               float* __restrict__ wout)
{
    long row = blockIdx.x;
    int l = threadIdx.x;
    int c = l & 15, chunk = l >> 4;

    const float* fr = flat + row * FDIM;
    float s = 0.f;
    int kbeg = chunk * 256;
#pragma unroll 4
    for (int k = kbeg; k < kbeg + 256; ++k)
        s = fmaf(fr[k], skipW[k * 16 + c], s);
    s += __shfl_xor(s, 16);
    s += __shfl_xor(s, 32);
    float skip = s + skipb[c];

    const float* hr = h1 + row * HDIM;
    float t = 0.f;
    int kb2 = chunk * 64;
#pragma unroll 4
    for (int k = kb2; k < kb2 + 64; ++k)
        t = fmaf(hr[k], W2[k * 16 + c], t);
    t += __shfl_xor(t, 16);
    t += __shfl_xor(t, 32);
    float h2 = t + b2[c];

    int cc = l & 31;
    float gval = bg[cc];
#pragma unroll
    for (int j = 0; j < 16; ++j)
        gval = fmaf(__shfl(h2, j), Wg[j * 32 + cc], gval);

    float a2    = __shfl(gval, c);
    float gate2 = __shfl(gval, c + 16);
    float sv = skip + a2 * (1.f / (1.f + __expf(-gate2)));

    float sum = sv, sq = sv * sv;
#pragma unroll
    for (int m = 1; m < 16; m <<= 1) {
        sum += __shfl_xor(sum, m);
        sq  += __shfl_xor(sq, m);
    }
    float mean = sum * (1.f / 16.f);
    float var  = sq * (1.f / 16.f) - mean * mean;
    float logit = (sv - mean) * rsqrtf(var + 1e-5f) * gamma[c] + beta[c];

    float mx = logit;
#pragma unroll
    for (int m = 1; m < 16; m <<= 1) mx = fmaxf(mx, __shfl_xor(mx, m));
    float e = __expf(logit - mx);
    float es = e;
#pragma unroll
    for (int m = 1; m < 16; m <<= 1) es += __shfl_xor(es, m);
    float w = e / es;
    if (l < 16) wout[row * NVAR + l] = w;
}

// ---------------------------------------------------------------------------
// Per-variable combine (bf16 inputs): pv = LN(skip + a*sig(gate)); sel += pv*w
// ---------------------------------------------------------------------------
__global__ __launch_bounds__(256)
void combine_sel(const __bf16* __restrict__ skipb, const __bf16* __restrict__ gbuf,
                 const float* __restrict__ gamma, const float* __restrict__ beta,
                 const float* __restrict__ wsm, float* __restrict__ sel, int n)
{
    __shared__ float red[8];
    long row = blockIdx.x;
    int c = threadIdx.x;
    float a = (float)gbuf[row * 512 + c];
    float g = (float)gbuf[row * 512 + 256 + c];
    float s = (float)skipb[row * 256 + c] + a * (1.f / (1.f + __expf(-g)));

    float sum = s, sq = s * s;
#pragma unroll
    for (int m = 1; m < 64; m <<= 1) {
        sum += __shfl_xor(sum, m);
        sq  += __shfl_xor(sq, m);
    }
    int wid = c >> 6, lane = c & 63;
    if (lane == 0) { red[wid] = sum; red[4 + wid] = sq; }
    __syncthreads();
    sum = red[0] + red[1] + red[2] + red[3];
    sq  = red[4] + red[5] + red[6] + red[7];
    float mean = sum * (1.f / 256.f);
    float var  = sq * (1.f / 256.f) - mean * mean;
    float pv = (s - mean) * rsqrtf(var + 1e-5f) * gamma[n * 256 + c] + beta[n * 256 + c];
    float wv = wsm[row * NVAR + n];
    long idx = row * 256 + c;
    float prev = (n == 0) ? 0.f : sel[idx];
    sel[idx] = prev + pv * wv;
}

// ---------------------------------------------------------------------------
// K5: output GRN, fused per 8-row block
// ---------------------------------------------------------------------------
#define R5 8
__global__ __launch_bounds__(256)
void k5_out(const float* __restrict__ sel,
            const float* __restrict__ W1, const float* __restrict__ b1,
            const float* __restrict__ W2, const float* __restrict__ b2,
            const float* __restrict__ Wg, const float* __restrict__ bg,
            const float* __restrict__ gamma, const float* __restrict__ beta,
            float* __restrict__ out)
{
    __shared__ float ss[R5][256];
    __shared__ float hs[R5][256];
    __shared__ float h2s[R5][256];
    __shared__ float red[8];
    int c = threadIdx.x;
    long row0 = (long)blockIdx.x * R5;

#pragma unroll
    for (int r = 0; r < R5; ++r) ss[r][c] = sel[(row0 + r) * 256 + c];
    __syncthreads();

    float acc[R5];
#pragma unroll
    for (int r = 0; r < R5; ++r) acc[r] = b1[c];
    for (int k = 0; k < 256; ++k) {
        float wv = W1[k * 256 + c];
#pragma unroll
        for (int r = 0; r < R5; ++r) acc[r] = fmaf(ss[r][k], wv, acc[r]);
    }
#pragma unroll
    for (int r = 0; r < R5; ++r) {
        float v = acc[r];
        hs[r][c] = v > 0.f ? v : (__expf(v) - 1.f);
    }
    __syncthreads();

#pragma unroll
    for (int r = 0; r < R5; ++r) acc[r] = b2[c];
    for (int k = 0; k < 256; ++k) {
        float wv = W2[k * 256 + c];
#pragma unroll
        for (int r = 0; r < R5; ++r) acc[r] = fmaf(hs[r][k], wv, acc[r]);
    }
#pragma unroll
    for (int r = 0; r < R5; ++r) h2s[r][c] = acc[r];
    __syncthreads();

    float aacc[R5], gacc[R5];
#pragma unroll
    for (int r = 0; r < R5; ++r) { aacc[r] = bg[c]; gacc[r] = bg[256 + c]; }
    for (int k = 0; k < 256; ++k) {
        float wa = Wg[k * 512 + c];
        float wg2 = Wg[k * 512 + 256 + c];
#pragma unroll
        for (int r = 0; r < R5; ++r) {
            aacc[r] = fmaf(h2s[r][k], wa, aacc[r]);
            gacc[r] = fmaf(h2s[r][k], wg2, gacc[r]);
        }
    }

    int wid = c >> 6, lane = c & 63;
    for (int r = 0; r < R5; ++r) {
        float s = ss[r][c] + aacc[r] * (1.f / (1.f + __expf(-gacc[r])));
        float sum = s, sq = s * s;
#pragma unroll
        for (int m = 1; m < 64; m <<= 1) {
            sum += __shfl_xor(sum, m);
            sq  += __shfl_xor(sq, m);
        }
        __syncthreads();
        if (lane == 0) { red[wid] = sum; red[4 + wid] = sq; }
        __syncthreads();
        sum = red[0] + red[1] + red[2] + red[3];
        sq  = red[4] + red[5] + red[6] + red[7];
        float mean = sum * (1.f / 256.f);
        float var  = sq * (1.f / 256.f) - mean * mean;
        out[(row0 + r) * 256 + c] = (s - mean) * rsqrtf(var + 1e-5f) * gamma[c] + beta[c];
    }
}

// ---------------------------------------------------------------------------
extern "C" void kernel_launch(void* const* d_in, const int* in_sizes, int n_in,
                              void* d_out, int out_size, void* d_ws, size_t ws_size,
                              hipStream_t stream)
{
    const float* vars     = (const float*)d_in[0];
    const float* ctx      = (const float*)d_in[1];
    const float* fg_W1    = (const float*)d_in[2];
    const float* fg_b1    = (const float*)d_in[3];
    const float* fg_Wc    = (const float*)d_in[4];
    const float* fg_W2    = (const float*)d_in[5];
    const float* fg_b2    = (const float*)d_in[6];
    const float* fg_Wg    = (const float*)d_in[7];
    const float* fg_bg    = (const float*)d_in[8];
    const float* fg_skipW = (const float*)d_in[9];
    const float* fg_skipb = (const float*)d_in[10];
    const float* fg_gamma = (const float*)d_in[11];
    const float* fg_beta  = (const float*)d_in[12];
    const float* vg_W1    = (const float*)d_in[13];
    const float* vg_b1    = (const float*)d_in[14];
    const float* vg_W2    = (const float*)d_in[15];
    const float* vg_b2    = (const float*)d_in[16];
    const float* vg_Wg    = (const float*)d_in[17];
    const float* vg_bg    = (const float*)d_in[18];
    const float* vg_skipW = (const float*)d_in[19];
    const float* vg_skipb = (const float*)d_in[20];
    const float* vg_gamma = (const float*)d_in[21];
    const float* vg_beta  = (const float*)d_in[22];
    const float* og_W1    = (const float*)d_in[23];
    const float* og_b1    = (const float*)d_in[24];
    const float* og_W2    = (const float*)d_in[25];
    const float* og_b2    = (const float*)d_in[26];
    const float* og_Wg    = (const float*)d_in[27];
    const float* og_bg    = (const float*)d_in[28];
    const float* og_gamma = (const float*)d_in[29];
    const float* og_beta  = (const float*)d_in[30];

    float* out = (float*)d_out;
    float* wsm = out + (long)BT * ODIM;

    // workspace layout (bytes)
    char* W = (char*)d_ws;
    size_t o = 0;
    __bf16* tW1 = (__bf16*)(W + o); o += (size_t)16 * 256 * 64 * 2;    // 524288
    __bf16* tW2 = (__bf16*)(W + o); o += (size_t)16 * 256 * 256 * 2;   // 2097152
    __bf16* tWg = (__bf16*)(W + o); o += (size_t)16 * 512 * 256 * 2;   // 4194304
    __bf16* tSk = (__bf16*)(W + o); o += (size_t)16 * 256 * 64 * 2;    // 524288
    __bf16* xb  = (__bf16*)(W + o); o += (size_t)BT * 64 * 2;          // 2097152
    char*   s1b = W + o;            o += (size_t)BT * 256 * 2;         // 8388608
    char*   s2b = W + o;            o += (size_t)BT * 256 * 2;
    char*   s3b = W + o;            o += (size_t)BT * 256 * 2;         // gb = s3+s4
    char*   s4b = W + o;            o += (size_t)BT * 256 * 2;
    float*  sel = (float*)(W + o);  o += (size_t)BT * 256 * 4;         // 16777216
    float*  ctxh= (float*)(W + o);  o += (size_t)64 * 256 * 4;
    (void)s4b;

    __bf16* s1 = (__bf16*)s1b;
    __bf16* s2 = (__bf16*)s2b;
    __bf16* gb = (__bf16*)s3b;      // [BT,512] spans s3+s4
    float*  h1 = (float*)s1b;       // [BT,256] f32 spans s1+s2 (pre-loop only)

    dim3 blk(256);

    // repack vg weights -> [N][K] bf16 (one launch)
    repack_w<<<dim3(128, 16, 4), blk, 0, stream>>>(vg_W1, vg_W2, vg_Wg, vg_skipW,
                                                   tW1, tW2, tWg, tSk);
    // K0: ctxh = context @ fg_Wc
    gemm_f32<<<dim3(4, 1), blk, 0, stream>>>(ctx, fg_Wc, nullptr, ctxh,
                                             64, CDIM, HDIM, HDIM, nullptr, 0);
    // K1: h1 = elu(flat @ fg_W1 + b1 + ctxh[b])   (f32)
    gemm_f32<<<dim3(4, 256), blk, 0, stream>>>(vars, fg_W1, fg_b1, h1,
                                               FDIM, FDIM, HDIM, HDIM, ctxh, 1);
    // K2: logits + softmax -> w
    k2_logits<<<BT, 64, 0, stream>>>(vars, h1, fg_skipW, fg_skipb,
                                     fg_W2, fg_b2, fg_Wg, fg_bg,
                                     fg_gamma, fg_beta, wsm);

    for (int n = 0; n < NVAR; ++n) {
        conv_x<<<1024, blk, 0, stream>>>(vars, xb, n);
        // hb = elu(xb @ W1_n)           -> s1
        gemm_bf16<<<dim3(2, 128), blk, 0, stream>>>(xb, tW1 + n * 256 * 64,
                                                    vg_b1 + n * 256, s1,
                                                    64, 64, 64, 256, 1);
        // h2b = hb @ W2_n               -> s2
        gemm_bf16<<<dim3(2, 128), blk, 0, stream>>>(s1, tW2 + n * 256 * 256,
                                                    vg_b2 + n * 256, s2,
                                                    256, 256, 256, 256, 0);
        // gb = h2b @ Wg_n (N=512)       -> s3+s4
        gemm_bf16<<<dim3(4, 128), blk, 0, stream>>>(s2, tWg + n * 512 * 256,
                                                    vg_bg + n * 512, gb,
                                                    256, 256, 256, 512, 0);
        // skip = xb @ skipW_n           -> s1 (hb dead)
        gemm_bf16<<<dim3(2, 128), blk, 0, stream>>>(xb, tSk + n * 256 * 64,
                                                    vg_skipb + n * 256, s1,
                                                    64, 64, 64, 256, 0);
        // sel (+)= LN(skip + a*sig(gate)) * w[:,n]
        combine_sel<<<BT, blk, 0, stream>>>(s1, gb, vg_gamma, vg_beta, wsm, sel, n);
    }

    // K5: output GRN
    k5_out<<<BT / R5, blk, 0, stream>>>(sel, og_W1, og_b1, og_W2, og_b2,
                                        og_Wg, og_bg, og_gamma, og_beta, out);
}

// Round 3
// 878.896 us; speedup vs baseline: 3.2982x; 1.3985x over previous
//
#include <hip/hip_runtime.h>
#include <hip/hip_bf16.h>

#define BT    16384
#define NVAR  16
#define DDIM  64
#define FDIM  1024
#define HDIM  256
#define ODIM  256
#define CDIM  64

typedef __bf16 bf16x8 __attribute__((ext_vector_type(8)));
typedef __bf16 bf16x4 __attribute__((ext_vector_type(4)));
typedef float  f32x4  __attribute__((ext_vector_type(4)));

__device__ __forceinline__ void gload16(const void* g, void* l) {
    __builtin_amdgcn_global_load_lds((const __attribute__((address_space(1))) void*)g,
                                     (__attribute__((address_space(3))) void*)l, 16, 0, 0);
}

// ---------------------------------------------------------------------------
// bf16 MFMA GEMM: C = act(A @ Bt^T + bias [+rowAdd])
// 128x128 tile, BK=64, 256 threads (2x2 waves of 64x64), 16x16x32 MFMA.
// AF32: A is f32 in global, reg-stage-converted to bf16 LDS (same swizzle).
// Split-output: cols >= splitCol go to C2 (bias2, no act) at col-splitCol.
// ---------------------------------------------------------------------------
template<int AF32>
__global__ __launch_bounds__(256)
void gemm_mfma(const void* __restrict__ Araw, const __bf16* __restrict__ Bt,
               const float* __restrict__ bias, const float* __restrict__ bias2,
               __bf16* __restrict__ C, __bf16* __restrict__ C2,
               int K, int lda, int ldb, int ldc, int ldc2,
               const float* __restrict__ rowAdd, int act, int splitCol)
{
    __shared__ char smem[32768];
    char* As = smem;
    char* Bs = smem + 16384;

    const int tid  = threadIdx.x;
    const int lane = tid & 63;
    const int wid  = tid >> 6;
    const int wr   = wid >> 1, wc = wid & 1;
    const int lr   = lane & 15, lc = lane >> 4;
    const long row0 = (long)blockIdx.y * 128;
    const int  col0 = blockIdx.x * 128;
    const int ldsbase = (tid & ~63) << 4;

    f32x4 acc[4][4] = {};
    int rA[4], rB[4];
#pragma unroll
    for (int i = 0; i < 4; ++i) { rA[i] = wr * 64 + i * 16 + lr; rB[i] = wc * 64 + i * 16 + lr; }

    const int nk = K >> 6;
    for (int kt = 0; kt < nk; ++kt) {
        const int k0 = kt << 6;
        __syncthreads();
#pragma unroll
        for (int s = 0; s < 4; ++s) {
            int q  = s * 256 + tid;
            int r  = q >> 3, cs = q & 7;
            int cg = cs ^ (r & 7);
            if (AF32 != 0) {
                const float* src = (const float*)Araw + (row0 + r) * (long)lda + k0 + (cg << 3);
                float4 u0 = *(const float4*)src;
                float4 u1 = *(const float4*)(src + 4);
                bf16x8 o;
                o[0] = (__bf16)u0.x; o[1] = (__bf16)u0.y; o[2] = (__bf16)u0.z; o[3] = (__bf16)u0.w;
                o[4] = (__bf16)u1.x; o[5] = (__bf16)u1.y; o[6] = (__bf16)u1.z; o[7] = (__bf16)u1.w;
                *(bf16x8*)(As + q * 16) = o;
            } else {
                gload16((const __bf16*)Araw + (row0 + r) * (long)lda + k0 + (cg << 3),
                        As + (s << 12) + ldsbase);
            }
            gload16(Bt + (long)(col0 + r) * ldb + k0 + (cg << 3), Bs + (s << 12) + ldsbase);
        }
        __syncthreads();
#pragma unroll
        for (int ks = 0; ks < 2; ++ks) {
            bf16x8 af[4], bfr[4];
#pragma unroll
            for (int i = 0; i < 4; ++i) {
                int c = ks * 4 + lc;
                af[i]  = *(const bf16x8*)(As + rA[i] * 128 + ((c ^ (rA[i] & 7)) << 4));
                bfr[i] = *(const bf16x8*)(Bs + rB[i] * 128 + ((c ^ (rB[i] & 7)) << 4));
            }
#pragma unroll
            for (int i = 0; i < 4; ++i)
#pragma unroll
                for (int j = 0; j < 4; ++j)
                    acc[i][j] = __builtin_amdgcn_mfma_f32_16x16x32_bf16(af[i], bfr[j], acc[i][j], 0, 0, 0);
        }
    }

#pragma unroll
    for (int j = 0; j < 4; ++j) {
        int col = col0 + wc * 64 + j * 16 + lr;
        bool hi = col >= splitCol;
        float bv = hi ? bias2[col - splitCol] : bias[col];
#pragma unroll
        for (int i = 0; i < 4; ++i) {
            f32x4 v = acc[i][j];
#pragma unroll
            for (int q = 0; q < 4; ++q) {
                long row = row0 + wr * 64 + i * 16 + lc * 4 + q;
                float x = v[q] + bv;
                if (rowAdd) x += rowAdd[(row >> 8) * (long)ldc + col];
                if (act && !hi) x = x > 0.f ? x : (__expf(x) - 1.f);
                if (hi) C2[row * (long)ldc2 + (col - splitCol)] = (__bf16)x;
                else    C [row * (long)ldc  + col]              = (__bf16)x;
            }
        }
    }
}

// ---------------------------------------------------------------------------
// Transpose+cast: in [K][N] f32 (z-grouped) -> out [N][K] bf16
// ---------------------------------------------------------------------------
__global__ __launch_bounds__(256)
void transpose_cast(const float* __restrict__ in, __bf16* __restrict__ out,
                    int K, int N, long inZ, long outZ)
{
    int z = blockIdx.y;
    in  += (long)z * inZ;
    out += (long)z * outZ;
    int tilesN = N >> 5;
    int tk = blockIdx.x / tilesN, tn = blockIdx.x % tilesN;
    __shared__ float t[32][33];
    int tid = threadIdx.x;
    int r = tid >> 3, c0 = (tid & 7) << 2;
    float4 v = *(const float4*)(in + (size_t)(tk * 32 + r) * N + tn * 32 + c0);
    t[r][c0] = v.x; t[r][c0 + 1] = v.y; t[r][c0 + 2] = v.z; t[r][c0 + 3] = v.w;
    __syncthreads();
    int nn = tid >> 3, k4 = (tid & 7) << 2;
    bf16x4 o;
    o[0] = (__bf16)t[k4 + 0][nn]; o[1] = (__bf16)t[k4 + 1][nn];
    o[2] = (__bf16)t[k4 + 2][nn]; o[3] = (__bf16)t[k4 + 3][nn];
    *(bf16x4*)(out + (size_t)(tn * 32 + nn) * K + tk * 32 + k4) = o;
}

// ---------------------------------------------------------------------------
// f32 tiled GEMM (setup-only: Wf = W2@Wg, ctxh) with z grouping
// ---------------------------------------------------------------------------
__global__ __launch_bounds__(256)
void gemm_f32z(const float* __restrict__ A, const float* __restrict__ B,
               float* __restrict__ C, int K, int lda, int ldb, int ldc,
               long aZ, long bZ, long cZ)
{
    int z = blockIdx.z;
    A += (long)z * aZ; B += (long)z * bZ; C += (long)z * cZ;
    __shared__ float As[16][68];
    __shared__ float Bs[16][68];
    int tid  = threadIdx.x;
    long brow = (long)blockIdx.y * 64;
    int  bcol = blockIdx.x * 64;
    int tr = tid >> 4, tc = tid & 15;
    int lrow = tid >> 2, lk = (tid & 3) << 2;
    int bk = tid >> 4,  bc = (tid & 15) << 2;

    const float* Ap = A + (brow + lrow) * (long)lda + lk;
    const float* Bp = B + (long)bk * ldb + bcol + bc;

    float acc[4][4] = {};
    for (int k0 = 0; k0 < K; k0 += 16) {
        float4 av = *(const float4*)(Ap + k0);
        float4 bv = *(const float4*)(Bp + (long)k0 * ldb);
        __syncthreads();
        As[lk + 0][lrow] = av.x;
        As[lk + 1][lrow] = av.y;
        As[lk + 2][lrow] = av.z;
        As[lk + 3][lrow] = av.w;
        *(float4*)&Bs[bk][bc] = bv;
        __syncthreads();
#pragma unroll
        for (int kk = 0; kk < 16; ++kk) {
            float4 a4 = *(const float4*)&As[kk][tr << 2];
            float4 b4 = *(const float4*)&Bs[kk][tc << 2];
            float ar[4] = {a4.x, a4.y, a4.z, a4.w};
            float br[4] = {b4.x, b4.y, b4.z, b4.w};
#pragma unroll
            for (int i = 0; i < 4; ++i)
#pragma unroll
                for (int j = 0; j < 4; ++j)
                    acc[i][j] = fmaf(ar[i], br[j], acc[i][j]);
        }
    }
#pragma unroll
    for (int i = 0; i < 4; ++i) {
        long row = brow + (tr << 2) + i;
#pragma unroll
        for (int j = 0; j < 4; ++j)
            C[row * (long)ldc + bcol + (tc << 2) + j] = acc[i][j];
    }
}

// bWf[n] = vg_b2[n]@vg_Wg[n] + vg_bg[n]  (n<16);  n==16: og variant
__global__ __launch_bounds__(512)
void bfuse(const float* __restrict__ vg_b2, const float* __restrict__ vg_Wg,
           const float* __restrict__ vg_bg, const float* __restrict__ og_b2,
           const float* __restrict__ og_Wg, const float* __restrict__ og_bg,
           float* __restrict__ bWf, float* __restrict__ ogbWf)
{
    int n = blockIdx.x, c = threadIdx.x;
    const float* b2 = n < 16 ? vg_b2 + n * 256 : og_b2;
    const float* Wg = n < 16 ? vg_Wg + (size_t)n * 131072 : og_Wg;
    const float* bg = n < 16 ? vg_bg + n * 512 : og_bg;
    float* dst      = n < 16 ? bWf + n * 512 : ogbWf;
    float s = bg[c];
    for (int k = 0; k < 256; ++k) s = fmaf(b2[k], Wg[k * 512 + c], s);
    dst[c] = s;
}

// fgWf[k][c] = sum_j fg_W2[k][j]*fg_Wg[j][c];  fgbf[c] = fg_b2@fg_Wg + fg_bg
__global__ __launch_bounds__(256)
void fgfuse(const float* __restrict__ W2, const float* __restrict__ Wg,
            const float* __restrict__ b2, const float* __restrict__ bg,
            float* __restrict__ Wf, float* __restrict__ bf)
{
    int c = blockIdx.x, k = threadIdx.x;
    float s = 0.f;
#pragma unroll
    for (int j = 0; j < 16; ++j) s = fmaf(W2[k * 16 + j], Wg[j * 32 + c], s);
    Wf[k * 32 + c] = s;
    if (k == 0) {
        float t = bg[c];
#pragma unroll
        for (int j = 0; j < 16; ++j) t = fmaf(b2[j], Wg[j * 32 + c], t);
        bf[c] = t;
    }
}

// ---------------------------------------------------------------------------
// K2: flatten-GRN tail (skip GEMV K=1024 + fused h1@Wf + LN16 + softmax16)
// One wave per row.
// ---------------------------------------------------------------------------
__global__ __launch_bounds__(64)
void k2_logits(const float* __restrict__ flat, const __bf16* __restrict__ h1,
               const float* __restrict__ skipW, const float* __restrict__ skipb,
               const float* __restrict__ Wf, const float* __restrict__ bf,
               const float* __restrict__ gamma, const float* __restrict__ beta,
               float* __restrict__ wout)
{
    long row = blockIdx.x;
    int l = threadIdx.x;
    int c = l & 15, chunk = l >> 4;

    const float* fr = flat + row * FDIM;
    float s = 0.f;
    int kbeg = chunk * 256;
#pragma unroll 4
    for (int k = kbeg; k < kbeg + 256; ++k)
        s = fmaf(fr[k], skipW[k * 16 + c], s);
    s += __shfl_xor(s, 16);
    s += __shfl_xor(s, 32);
    float skip = s + skipb[c];

    // g = h1 @ Wf + bf  (K=256 -> 32 outputs), lane l -> cc=l&31, half=l>>5
    const __bf16* hr = h1 + row * HDIM;
    int cc = l & 31, half = l >> 5;
    float g = 0.f;
    int kb = half * 128;
#pragma unroll 4
    for (int k = kb; k < kb + 128; ++k)
        g = fmaf((float)hr[k], Wf[k * 32 + cc], g);
    g += __shfl_xor(g, 32);
    g += bf[cc];

    float a2    = __shfl(g, c);
    float gate2 = __shfl(g, c + 16);
    float sv = skip + a2 * (1.f / (1.f + __expf(-gate2)));

    float sum = sv, sq = sv * sv;
#pragma unroll
    for (int m = 1; m < 16; m <<= 1) {
        sum += __shfl_xor(sum, m);
        sq  += __shfl_xor(sq, m);
    }
    float mean = sum * (1.f / 16.f);
    float var  = sq * (1.f / 16.f) - mean * mean;
    float logit = (sv - mean) * rsqrtf(var + 1e-5f) * gamma[c] + beta[c];

    float mx = logit;
#pragma unroll
    for (int m = 1; m < 16; m <<= 1) mx = fmaxf(mx, __shfl_xor(mx, m));
    float e = __expf(logit - mx);
    float es = e;
#pragma unroll
    for (int m = 1; m < 16; m <<= 1) es += __shfl_xor(es, m);
    float w = e / es;
    if (l < 16) wout[row * NVAR + l] = w;
}

// ---------------------------------------------------------------------------
// Per-variable combine: pv = LN(skip + a*sig(gate)); sel += pv*w[:,n]
// On the final call also emits selb (bf16 of final sel).
// ---------------------------------------------------------------------------
__global__ __launch_bounds__(256)
void combine_sel(const __bf16* __restrict__ sk, const __bf16* __restrict__ gbuf,
                 const float* __restrict__ gamma, const float* __restrict__ beta,
                 const float* __restrict__ wsm, float* __restrict__ sel,
                 __bf16* __restrict__ selb, int n)
{
    __shared__ float red[8];
    long row = blockIdx.x;
    int c = threadIdx.x;
    float a = (float)gbuf[row * 512 + c];
    float g = (float)gbuf[row * 512 + 256 + c];
    float s = (float)sk[row * 256 + c] + a * (1.f / (1.f + __expf(-g)));

    float sum = s, sq = s * s;
#pragma unroll
    for (int m = 1; m < 64; m <<= 1) {
        sum += __shfl_xor(sum, m);
        sq  += __shfl_xor(sq, m);
    }
    int wid = c >> 6, lane = c & 63;
    if (lane == 0) { red[wid] = sum; red[4 + wid] = sq; }
    __syncthreads();
    sum = red[0] + red[1] + red[2] + red[3];
    sq  = red[4] + red[5] + red[6] + red[7];
    float mean = sum * (1.f / 256.f);
    float var  = sq * (1.f / 256.f) - mean * mean;
    float pv = (s - mean) * rsqrtf(var + 1e-5f) * gamma[n * 256 + c] + beta[n * 256 + c];
    float wv = wsm[row * NVAR + n];
    long idx = row * 256 + c;
    float prev = (n == 0) ? 0.f : sel[idx];
    float cur = prev + pv * wv;
    sel[idx] = cur;
    if (selb) selb[idx] = (__bf16)cur;
}

// ---------------------------------------------------------------------------
// Output-GRN epilogue: out = LN(sel + a*sig(gate))
// ---------------------------------------------------------------------------
__global__ __launch_bounds__(256)
void k5_ln(const float* __restrict__ sel, const __bf16* __restrict__ gbuf,
           const float* __restrict__ gamma, const float* __restrict__ beta,
           float* __restrict__ out)
{
    __shared__ float red[8];
    long row = blockIdx.x;
    int c = threadIdx.x;
    float a = (float)gbuf[row * 512 + c];
    float g = (float)gbuf[row * 512 + 256 + c];
    float s = sel[row * 256 + c] + a * (1.f / (1.f + __expf(-g)));

    float sum = s, sq = s * s;
#pragma unroll
    for (int m = 1; m < 64; m <<= 1) {
        sum += __shfl_xor(sum, m);
        sq  += __shfl_xor(sq, m);
    }
    int wid = c >> 6, lane = c & 63;
    if (lane == 0) { red[wid] = sum; red[4 + wid] = sq; }
    __syncthreads();
    sum = red[0] + red[1] + red[2] + red[3];
    sq  = red[4] + red[5] + red[6] + red[7];
    float mean = sum * (1.f / 256.f);
    float var  = sq * (1.f / 256.f) - mean * mean;
    out[row * 256 + c] = (s - mean) * rsqrtf(var + 1e-5f) * gamma[c] + beta[c];
}

// ---------------------------------------------------------------------------
extern "C" void kernel_launch(void* const* d_in, const int* in_sizes, int n_in,
                              void* d_out, int out_size, void* d_ws, size_t ws_size,
                              hipStream_t stream)
{
    const float* vars     = (const float*)d_in[0];
    const float* ctx      = (const float*)d_in[1];
    const float* fg_W1    = (const float*)d_in[2];
    const float* fg_b1    = (const float*)d_in[3];
    const float* fg_Wc    = (const float*)d_in[4];
    const float* fg_W2    = (const float*)d_in[5];
    const float* fg_b2    = (const float*)d_in[6];
    const float* fg_Wg    = (const float*)d_in[7];
    const float* fg_bg    = (const float*)d_in[8];
    const float* fg_skipW = (const float*)d_in[9];
    const float* fg_skipb = (const float*)d_in[10];
    const float* fg_gamma = (const float*)d_in[11];
    const float* fg_beta  = (const float*)d_in[12];
    const float* vg_W1    = (const float*)d_in[13];
    const float* vg_b1    = (const float*)d_in[14];
    const float* vg_W2    = (const float*)d_in[15];
    const float* vg_b2    = (const float*)d_in[16];
    const float* vg_Wg    = (const float*)d_in[17];
    const float* vg_bg    = (const float*)d_in[18];
    const float* vg_skipW = (const float*)d_in[19];
    const float* vg_skipb = (const float*)d_in[20];
    const float* vg_gamma = (const float*)d_in[21];
    const float* vg_beta  = (const float*)d_in[22];
    const float* og_W1    = (const float*)d_in[23];
    const float* og_b1    = (const float*)d_in[24];
    const float* og_W2    = (const float*)d_in[25];
    const float* og_b2    = (const float*)d_in[26];
    const float* og_Wg    = (const float*)d_in[27];
    const float* og_bg    = (const float*)d_in[28];
    const float* og_gamma = (const float*)d_in[29];
    const float* og_beta  = (const float*)d_in[30];

    float* out = (float*)d_out;
    float* wsm = out + (long)BT * ODIM;

    // ---- workspace layout (~63 MB; R1 proved ws_size >= 67 MB) ----
    char* W = (char*)d_ws;
    size_t o = 0;
    auto alloc = [&](size_t b) { void* p = W + o; o += (b + 255) & ~(size_t)255; return p; };
    __bf16* tW1S  = (__bf16*)alloc((size_t)16 * 512 * 64 * 2);    // [n][W1|skip][64]
    __bf16* tWf   = (__bf16*)alloc((size_t)16 * 512 * 256 * 2);   // [n][512][256]
    __bf16* ogW1t = (__bf16*)alloc((size_t)256 * 256 * 2);
    __bf16* ogWft = (__bf16*)alloc((size_t)512 * 256 * 2);
    __bf16* fgW1t = (__bf16*)alloc((size_t)256 * 1024 * 2);
    float*  bWf   = (float*)alloc((size_t)16 * 512 * 4);
    float*  ogbWf = (float*)alloc((size_t)512 * 4);
    float*  fgWf  = (float*)alloc((size_t)256 * 32 * 4);
    float*  fgbf  = (float*)alloc((size_t)32 * 4);
    float*  ctxh  = (float*)alloc((size_t)64 * 256 * 4);
    __bf16* s1    = (__bf16*)alloc((size_t)BT * 256 * 2);
    __bf16* sk    = (__bf16*)alloc((size_t)BT * 256 * 2);
    __bf16* gb    = (__bf16*)alloc((size_t)BT * 512 * 2);
    float*  sel   = (float*)alloc((size_t)BT * 256 * 4);
    float*  Wf32  = (float*)gb;     // setup-time overlay: [17][256][512] f32

    dim3 blk(256);
    const int NOSPLIT = 1 << 30;

    // ---- setup: fused weights + repacks ----
    // Wf32[z] = W2[z] @ Wg[z]  (z<16 vg, z==16 og)
    gemm_f32z<<<dim3(8, 4, 16), blk, 0, stream>>>(vg_W2, vg_Wg, Wf32,
                                                  256, 256, 512, 512,
                                                  65536, 131072, 131072);
    gemm_f32z<<<dim3(8, 4, 1), blk, 0, stream>>>(og_W2, og_Wg, Wf32 + (size_t)16 * 131072,
                                                 256, 256, 512, 512, 0, 0, 0);
    bfuse<<<17, 512, 0, stream>>>(vg_b2, vg_Wg, vg_bg, og_b2, og_Wg, og_bg, bWf, ogbWf);
    fgfuse<<<32, 256, 0, stream>>>(fg_W2, fg_Wg, fg_b2, fg_bg, fgWf, fgbf);

    transpose_cast<<<dim3(16, 16), blk, 0, stream>>>(vg_W1, tW1S, 64, 256,
                                                     64 * 256, 512 * 64);
    transpose_cast<<<dim3(16, 16), blk, 0, stream>>>(vg_skipW, tW1S + 256 * 64, 64, 256,
                                                     64 * 256, 512 * 64);
    transpose_cast<<<dim3(128, 16), blk, 0, stream>>>(Wf32, tWf, 256, 512,
                                                      131072, 512 * 256);
    transpose_cast<<<dim3(128, 1), blk, 0, stream>>>(Wf32 + (size_t)16 * 131072, ogWft,
                                                     256, 512, 0, 0);
    transpose_cast<<<dim3(64, 1), blk, 0, stream>>>(og_W1, ogW1t, 256, 256, 0, 0);
    transpose_cast<<<dim3(256, 1), blk, 0, stream>>>(fg_W1, fgW1t, 1024, 256, 0, 0);

    // ctxh = context @ fg_Wc   [64,64]@[64,256]
    gemm_f32z<<<dim3(4, 1, 1), blk, 0, stream>>>(ctx, fg_Wc, ctxh, 64, CDIM, HDIM, HDIM, 0, 0, 0);

    // ---- flatten GRN ----
    // h1 = elu(flat @ fg_W1 + b1 + ctxh[b])  (f32 A, MFMA)
    gemm_mfma<1><<<dim3(2, 128), blk, 0, stream>>>(vars, fgW1t, fg_b1, nullptr,
                                                   s1, nullptr, FDIM, FDIM, FDIM, HDIM, 0,
                                                   ctxh, 1, NOSPLIT);
    k2_logits<<<BT, 64, 0, stream>>>(vars, s1, fg_skipW, fg_skipb,
                                     fgWf, fgbf, fg_gamma, fg_beta, wsm);

    // ---- per-variable GRNs ----
    for (int n = 0; n < NVAR; ++n) {
        // [hb|skip] = [elu | id](x_n @ [W1|skipW] + [b1|skipb])   K=64, N=512
        gemm_mfma<1><<<dim3(4, 128), blk, 0, stream>>>(vars + n * DDIM,
                                                       tW1S + (size_t)n * 512 * 64,
                                                       vg_b1 + n * 256, vg_skipb + n * 256,
                                                       s1, sk, 64, FDIM, 64, HDIM, HDIM,
                                                       nullptr, 1, 256);
        // gb = hb @ Wf_n + bWf_n   K=256, N=512
        gemm_mfma<0><<<dim3(4, 128), blk, 0, stream>>>(s1, tWf + (size_t)n * 512 * 256,
                                                       bWf + n * 512, nullptr,
                                                       gb, nullptr, 256, HDIM, HDIM, 512, 0,
                                                       nullptr, 0, NOSPLIT);
        combine_sel<<<BT, blk, 0, stream>>>(sk, gb, vg_gamma, vg_beta, wsm, sel,
                                            (n == NVAR - 1) ? sk : nullptr, n);
    }

    // ---- output GRN ----
    // h5 = elu(selb @ og_W1 + b1)
    gemm_mfma<0><<<dim3(2, 128), blk, 0, stream>>>(sk, ogW1t, og_b1, nullptr,
                                                   s1, nullptr, 256, HDIM, HDIM, HDIM, 0,
                                                   nullptr, 1, NOSPLIT);
    // g5 = h5 @ ogWf + ogbWf   N=512
    gemm_mfma<0><<<dim3(4, 128), blk, 0, stream>>>(s1, ogWft, ogbWf, nullptr,
                                                   gb, nullptr, 256, HDIM, HDIM, 512, 0,
                                                   nullptr, 0, NOSPLIT);
    k5_ln<<<BT, blk, 0, stream>>>(sel, gb, og_gamma, og_beta, out);
}

// Round 4
// 849.802 us; speedup vs baseline: 3.4111x; 1.0342x over previous
//
#include <hip/hip_runtime.h>
#include <hip/hip_bf16.h>

#define BT    16384
#define NVAR  16
#define DDIM  64
#define FDIM  1024
#define HDIM  256
#define ODIM  256
#define CDIM  64
#define SELP  258      // padded sel row stride (f32) to spread LDS banks

typedef __bf16 bf16x8 __attribute__((ext_vector_type(8)));
typedef __bf16 bf16x4 __attribute__((ext_vector_type(4)));
typedef float  f32x4  __attribute__((ext_vector_type(4)));

__device__ __forceinline__ void gload16(const void* g, void* l) {
    __builtin_amdgcn_global_load_lds((const __attribute__((address_space(1))) void*)g,
                                     (__attribute__((address_space(3))) void*)l, 16, 0, 0);
}

// ---------------------------------------------------------------------------
// bf16 MFMA GEMM (128x128 tile, BK=64, 4 waves). AF32: A is f32 (reg-staged
// convert). Split-output: cols >= splitCol -> C2 (bias2, no act, no rowAdd).
// z-batched via zA/zB/zC element strides.
// ---------------------------------------------------------------------------
template<int AF32>
__global__ __launch_bounds__(256)
void gemm_mfma(const void* __restrict__ Araw, const __bf16* __restrict__ Bt,
               const float* __restrict__ bias, const float* __restrict__ bias2,
               __bf16* __restrict__ C, __bf16* __restrict__ C2,
               int K, int lda, int ldb, int ldc, int ldc2,
               const float* __restrict__ rowAdd, int act, int splitCol,
               long zA, long zB, long zC)
{
    __shared__ char smem[32768];
    char* As = smem;
    char* Bs = smem + 16384;

    const int z = blockIdx.z;
    const __bf16* Btz = Bt + z * zB;

    const int tid  = threadIdx.x;
    const int lane = tid & 63;
    const int wid  = tid >> 6;
    const int wr   = wid >> 1, wc = wid & 1;
    const int lr   = lane & 15, lc = lane >> 4;
    const long row0 = (long)blockIdx.y * 128;
    const int  col0 = blockIdx.x * 128;
    const int ldsbase = (tid & ~63) << 4;

    f32x4 acc[4][4] = {};
    int rA[4], rB[4];
#pragma unroll
    for (int i = 0; i < 4; ++i) { rA[i] = wr * 64 + i * 16 + lr; rB[i] = wc * 64 + i * 16 + lr; }

    const int nk = K >> 6;
    for (int kt = 0; kt < nk; ++kt) {
        const int k0 = kt << 6;
        __syncthreads();
#pragma unroll
        for (int s = 0; s < 4; ++s) {
            int q  = s * 256 + tid;
            int r  = q >> 3, cs = q & 7;
            int cg = cs ^ (r & 7);
            if (AF32 != 0) {
                const float* src = (const float*)Araw + z * zA + (row0 + r) * (long)lda + k0 + (cg << 3);
                float4 u0 = *(const float4*)src;
                float4 u1 = *(const float4*)(src + 4);
                bf16x8 o;
                o[0] = (__bf16)u0.x; o[1] = (__bf16)u0.y; o[2] = (__bf16)u0.z; o[3] = (__bf16)u0.w;
                o[4] = (__bf16)u1.x; o[5] = (__bf16)u1.y; o[6] = (__bf16)u1.z; o[7] = (__bf16)u1.w;
                *(bf16x8*)(As + q * 16) = o;
            } else {
                gload16((const __bf16*)Araw + z * zA + (row0 + r) * (long)lda + k0 + (cg << 3),
                        As + (s << 12) + ldsbase);
            }
            gload16(Btz + (long)(col0 + r) * ldb + k0 + (cg << 3), Bs + (s << 12) + ldsbase);
        }
        __syncthreads();
#pragma unroll
        for (int ks = 0; ks < 2; ++ks) {
            bf16x8 af[4], bfr[4];
#pragma unroll
            for (int i = 0; i < 4; ++i) {
                int c = ks * 4 + lc;
                af[i]  = *(const bf16x8*)(As + rA[i] * 128 + ((c ^ (rA[i] & 7)) << 4));
                bfr[i] = *(const bf16x8*)(Bs + rB[i] * 128 + ((c ^ (rB[i] & 7)) << 4));
            }
#pragma unroll
            for (int i = 0; i < 4; ++i)
#pragma unroll
                for (int j = 0; j < 4; ++j)
                    acc[i][j] = __builtin_amdgcn_mfma_f32_16x16x32_bf16(af[i], bfr[j], acc[i][j], 0, 0, 0);
        }
    }

#pragma unroll
    for (int j = 0; j < 4; ++j) {
        int col = col0 + wc * 64 + j * 16 + lr;
        bool hi = col >= splitCol;
        float bv = hi ? bias2[col - splitCol] : (bias ? bias[col] : 0.f);
#pragma unroll
        for (int i = 0; i < 4; ++i) {
            f32x4 v = acc[i][j];
#pragma unroll
            for (int q = 0; q < 4; ++q) {
                long row = row0 + wr * 64 + i * 16 + lc * 4 + q;
                float x = v[q] + bv;
                if (rowAdd && !hi) x += rowAdd[(row >> 8) * (long)ldc + col];
                if (act && !hi)    x = x > 0.f ? x : (__expf(x) - 1.f);
                if (hi) C2[z * zC + row * (long)ldc2 + (col - splitCol)] = (__bf16)x;
                else    C [z * zC + row * (long)ldc  + col]              = (__bf16)x;
            }
        }
    }
}

// ---------------------------------------------------------------------------
// Transpose+cast: in [K][N] f32 (z-grouped) -> out [N][K] bf16
// ---------------------------------------------------------------------------
__global__ __launch_bounds__(256)
void transpose_cast(const float* __restrict__ in, __bf16* __restrict__ out,
                    int K, int N, long inZ, long outZ)
{
    int z = blockIdx.y;
    in  += (long)z * inZ;
    out += (long)z * outZ;
    int tilesN = N >> 5;
    int tk = blockIdx.x / tilesN, tn = blockIdx.x % tilesN;
    __shared__ float t[32][33];
    int tid = threadIdx.x;
    int r = tid >> 3, c0 = (tid & 7) << 2;
    float4 v = *(const float4*)(in + (size_t)(tk * 32 + r) * N + tn * 32 + c0);
    t[r][c0] = v.x; t[r][c0 + 1] = v.y; t[r][c0 + 2] = v.z; t[r][c0 + 3] = v.w;
    __syncthreads();
    int nn = tid >> 3, k4 = (tid & 7) << 2;
    bf16x4 o;
    o[0] = (__bf16)t[k4 + 0][nn]; o[1] = (__bf16)t[k4 + 1][nn];
    o[2] = (__bf16)t[k4 + 2][nn]; o[3] = (__bf16)t[k4 + 3][nn];
    *(bf16x4*)(out + (size_t)(tn * 32 + nn) * K + tk * 32 + k4) = o;
}

// ---------------------------------------------------------------------------
// Fragment packing: Bt[N][K] logical -> blocks of (nt,kt): 64 lanes x 16B.
// Block index bx = nt*(K/32)+kt; lane (lr=lane&15, lc=lane>>4) holds
// Bt[nt*16+lr][kt*32+lc*8 .. +8].
// ---------------------------------------------------------------------------
__global__ void frag_pack_bf16(const __bf16* __restrict__ src, __bf16* __restrict__ dst,
                               int K, int N, long srcZ, long dstZ)
{
    int z = blockIdx.y;
    src += (long)z * srcZ; dst += (long)z * dstZ;
    int KT = K >> 5;
    int nt = blockIdx.x / KT, kt = blockIdx.x % KT;
    int lane = threadIdx.x, lr = lane & 15, lc = lane >> 4;
    bf16x8 o;
#pragma unroll
    for (int e = 0; e < 8; ++e)
        o[e] = src[(size_t)(kt * 32 + lc * 8 + e) * N + nt * 16 + lr];
    *(bf16x8*)&dst[(size_t)blockIdx.x * 512 + lane * 8] = o;
}

__global__ void frag_pack_f32(const float* __restrict__ src, __bf16* __restrict__ dst,
                              int K, int N)
{
    int KT = K >> 5;
    int nt = blockIdx.x / KT, kt = blockIdx.x % KT;
    int lane = threadIdx.x, lr = lane & 15, lc = lane >> 4;
    bf16x8 o;
#pragma unroll
    for (int e = 0; e < 8; ++e)
        o[e] = (__bf16)src[(size_t)(kt * 32 + lc * 8 + e) * N + nt * 16 + lr];
    *(bf16x8*)&dst[(size_t)blockIdx.x * 512 + lane * 8] = o;
}

// W1S packed: N=512 (cols 0..255 = W1_n, 256..511 = skipW_n), K=64.
__global__ void frag_pack_w1s(const float* __restrict__ W1, const float* __restrict__ Sk,
                              __bf16* __restrict__ dst)
{
    int n = blockIdx.y;
    int nt = blockIdx.x >> 1, kt = blockIdx.x & 1;
    const float* src = (nt < 16) ? W1 + (size_t)n * 16384 : Sk + (size_t)n * 16384;
    int lane = threadIdx.x, lr = lane & 15, lc = lane >> 4;
    int col = (nt & 15) * 16 + lr;
    bf16x8 o;
#pragma unroll
    for (int e = 0; e < 8; ++e)
        o[e] = (__bf16)src[(size_t)(kt * 32 + lc * 8 + e) * 256 + col];
    *(bf16x8*)&dst[((size_t)n * 64 + blockIdx.x) * 512 + lane * 8] = o;
}

// Pad rows 256..383 of Btk1 with skipW^T (cols>=16 zero) + padded bias2.
__global__ __launch_bounds__(256)
void pad_skip(const float* __restrict__ skW, const float* __restrict__ skb,
              __bf16* __restrict__ Btk1, float* __restrict__ bias2)
{
    int r = blockIdx.x;            // 0..127
    for (int k = threadIdx.x; k < 1024; k += 256)
        Btk1[(size_t)(256 + r) * 1024 + k] = (r < 16) ? (__bf16)skW[k * 16 + r] : (__bf16)0.f;
    if (threadIdx.x == 0) bias2[r] = (r < 16) ? skb[r] : 0.f;
}

// ---------------------------------------------------------------------------
// f32 tiled GEMM (setup: ctxh)
// ---------------------------------------------------------------------------
__global__ __launch_bounds__(256)
void gemm_f32z(const float* __restrict__ A, const float* __restrict__ B,
               float* __restrict__ C, int K, int lda, int ldb, int ldc)
{
    __shared__ float As[16][68];
    __shared__ float Bs[16][68];
    int tid  = threadIdx.x;
    long brow = (long)blockIdx.y * 64;
    int  bcol = blockIdx.x * 64;
    int tr = tid >> 4, tc = tid & 15;
    int lrow = tid >> 2, lk = (tid & 3) << 2;
    int bk = tid >> 4,  bc = (tid & 15) << 2;

    const float* Ap = A + (brow + lrow) * (long)lda + lk;
    const float* Bp = B + (long)bk * ldb + bcol + bc;

    float acc[4][4] = {};
    for (int k0 = 0; k0 < K; k0 += 16) {
        float4 av = *(const float4*)(Ap + k0);
        float4 bv = *(const float4*)(Bp + (long)k0 * ldb);
        __syncthreads();
        As[lk + 0][lrow] = av.x;
        As[lk + 1][lrow] = av.y;
        As[lk + 2][lrow] = av.z;
        As[lk + 3][lrow] = av.w;
        *(float4*)&Bs[bk][bc] = bv;
        __syncthreads();
#pragma unroll
        for (int kk = 0; kk < 16; ++kk) {
            float4 a4 = *(const float4*)&As[kk][tr << 2];
            float4 b4 = *(const float4*)&Bs[kk][tc << 2];
            float ar[4] = {a4.x, a4.y, a4.z, a4.w};
            float br[4] = {b4.x, b4.y, b4.z, b4.w};
#pragma unroll
            for (int i = 0; i < 4; ++i)
#pragma unroll
                for (int j = 0; j < 4; ++j)
                    acc[i][j] = fmaf(ar[i], br[j], acc[i][j]);
        }
    }
#pragma unroll
    for (int i = 0; i < 4; ++i) {
        long row = brow + (tr << 2) + i;
#pragma unroll
        for (int j = 0; j < 4; ++j)
            C[row * (long)ldc + bcol + (tc << 2) + j] = acc[i][j];
    }
}

// bWf[n] = vg_b2[n]@vg_Wg[n] + vg_bg[n]  (n<16);  n==16: og variant
__global__ __launch_bounds__(512)
void bfuse(const float* __restrict__ vg_b2, const float* __restrict__ vg_Wg,
           const float* __restrict__ vg_bg, const float* __restrict__ og_b2,
           const float* __restrict__ og_Wg, const float* __restrict__ og_bg,
           float* __restrict__ bWf, float* __restrict__ ogbWf)
{
    int n = blockIdx.x, c = threadIdx.x;
    const float* b2 = n < 16 ? vg_b2 + n * 256 : og_b2;
    const float* Wg = n < 16 ? vg_Wg + (size_t)n * 131072 : og_Wg;
    const float* bg = n < 16 ? vg_bg + n * 512 : og_bg;
    float* dst      = n < 16 ? bWf + n * 512 : ogbWf;
    float s = bg[c];
    for (int k = 0; k < 256; ++k) s = fmaf(b2[k], Wg[k * 512 + c], s);
    dst[c] = s;
}

// fgWf = fg_W2 @ fg_Wg [256][32] f32; fgbf = fg_b2@fg_Wg + fg_bg
__global__ __launch_bounds__(256)
void fgfuse(const float* __restrict__ W2, const float* __restrict__ Wg,
            const float* __restrict__ b2, const float* __restrict__ bg,
            float* __restrict__ Wf, float* __restrict__ bf)
{
    int c = blockIdx.x, k = threadIdx.x;
    float s = 0.f;
#pragma unroll
    for (int j = 0; j < 16; ++j) s = fmaf(W2[k * 16 + j], Wg[j * 32 + c], s);
    Wf[k * 32 + c] = s;
    if (k == 0) {
        float t = bg[c];
#pragma unroll
        for (int j = 0; j < 16; ++j) t = fmaf(b2[j], Wg[j * 32 + c], t);
        bf[c] = t;
    }
}

// ---------------------------------------------------------------------------
// K2 (light): g = h1@fgWf + skip16; LN16 + softmax16 -> w. 4 rows/block.
// ---------------------------------------------------------------------------
__global__ __launch_bounds__(256)
void k2_logits(const __bf16* __restrict__ h1, const __bf16* __restrict__ skip16,
               const float* __restrict__ Wf, const float* __restrict__ bf,
               const float* __restrict__ gamma, const float* __restrict__ beta,
               float* __restrict__ wout)
{
    __shared__ float hrow[4][256];
    int l = threadIdx.x & 63, wv_ = threadIdx.x >> 6;
    long row = (long)blockIdx.x * 4 + wv_;

    bf16x4 hv = *(const bf16x4*)(h1 + row * 256 + l * 4);
    float4 hf; hf.x = (float)hv[0]; hf.y = (float)hv[1]; hf.z = (float)hv[2]; hf.w = (float)hv[3];
    *(float4*)&hrow[wv_][l * 4] = hf;

    int cc = l & 31, half = l >> 5;
    float g = 0.f;
    int kb = half * 128;
#pragma unroll 4
    for (int k = kb; k < kb + 128; ++k)
        g = fmaf(hrow[wv_][k], Wf[k * 32 + cc], g);
    g += __shfl_xor(g, 32);
    g += bf[cc];

    int c = l & 15;
    float a2    = __shfl(g, c);
    float gate2 = __shfl(g, c + 16);
    float skip  = (float)skip16[row * 128 + c];
    float sv = skip + a2 * (1.f / (1.f + __expf(-gate2)));

    float sum = sv, sq = sv * sv;
#pragma unroll
    for (int m = 1; m < 16; m <<= 1) {
        sum += __shfl_xor(sum, m);
        sq  += __shfl_xor(sq, m);
    }
    float mean = sum * (1.f / 16.f);
    float var  = sq * (1.f / 16.f) - mean * mean;
    float logit = (sv - mean) * rsqrtf(var + 1e-5f) * gamma[c] + beta[c];

    float mx = logit;
#pragma unroll
    for (int m = 1; m < 16; m <<= 1) mx = fmaxf(mx, __shfl_xor(mx, m));
    float e = __expf(logit - mx);
    float es = e;
#pragma unroll
    for (int m = 1; m < 16; m <<= 1) es += __shfl_xor(es, m);
    if (l < 16) wout[row * NVAR + l] = e / es;
}

// ---------------------------------------------------------------------------
// MEGA: per 64-row block, run all 16 per-variable GRNs + weighted sum + output
// GRN entirely in LDS. 256 threads (4 waves), 1 block/CU.
// ---------------------------------------------------------------------------
__global__ __launch_bounds__(256, 1)
void vsn_mega(const float* __restrict__ vars, const float* __restrict__ wsm,
              const __bf16* __restrict__ W1Sp, const __bf16* __restrict__ Wfp,
              const float* __restrict__ vg_b1, const float* __restrict__ vg_skipb,
              const float* __restrict__ bWf,
              const float* __restrict__ vg_gamma, const float* __restrict__ vg_beta,
              const __bf16* __restrict__ ogW1p, const __bf16* __restrict__ ogWfp,
              const float* __restrict__ og_b1, const float* __restrict__ ogbWf,
              const float* __restrict__ og_gamma, const float* __restrict__ og_beta,
              float* __restrict__ out)
{
    __shared__ __bf16 xb[64 * 64];        //  8 KB, 16B-chunk XOR swizzle
    __shared__ __bf16 hb[64 * 256];       // 32 KB, swizzled
    __shared__ __bf16 skb[64 * 256];      // 32 KB, swizzled
    __shared__ float  selL[64 * SELP];    // 66 KB, linear (padded stride)
    __shared__ float  red[64][4][2];      //  2 KB
    __shared__ float  wls[64 * 16];       //  4 KB

    const int tid = threadIdx.x;
    const int w   = tid >> 6, lane = tid & 63;
    const int lr  = lane & 15, lc = lane >> 4;
    const long row0 = (long)blockIdx.x * 64;

    for (int i = tid; i < 64 * 16; i += 256) wls[i] = wsm[row0 * 16 + i];
    for (int i = tid; i < 64 * SELP; i += 256) selL[i] = 0.f;

    for (int n = 0; n < NVAR; ++n) {
        __syncthreads();
        // ---- stage x_n [64][64] f32 -> xb bf16 swizzled ----
        {
            int r = tid >> 2, seg = tid & 3;
            const float* src = vars + (row0 + r) * FDIM + n * DDIM + seg * 16;
            float4 a0 = *(const float4*)(src);
            float4 a1 = *(const float4*)(src + 4);
            float4 a2 = *(const float4*)(src + 8);
            float4 a3 = *(const float4*)(src + 12);
            bf16x8 o0, o1;
            o0[0]=(__bf16)a0.x; o0[1]=(__bf16)a0.y; o0[2]=(__bf16)a0.z; o0[3]=(__bf16)a0.w;
            o0[4]=(__bf16)a1.x; o0[5]=(__bf16)a1.y; o0[6]=(__bf16)a1.z; o0[7]=(__bf16)a1.w;
            o1[0]=(__bf16)a2.x; o1[1]=(__bf16)a2.y; o1[2]=(__bf16)a2.z; o1[3]=(__bf16)a2.w;
            o1[4]=(__bf16)a3.x; o1[5]=(__bf16)a3.y; o1[6]=(__bf16)a3.z; o1[7]=(__bf16)a3.w;
            int c0 = (seg * 2)     ^ (r & 7);
            int c1 = (seg * 2 + 1) ^ (r & 7);
            *(bf16x8*)&xb[r * 64 + c0 * 8] = o0;
            *(bf16x8*)&xb[r * 64 + c1 * 8] = o1;
        }
        __syncthreads();

        // ---- GEMM1: xb @ W1S_n -> hb (elu, cols 0..255) | skb (cols 256..511) ----
        {
            f32x4 acc[4][8] = {};
            const __bf16* wbase = W1Sp + (size_t)n * 32768;
#pragma unroll
            for (int kt = 0; kt < 2; ++kt) {
                bf16x8 af[4];
#pragma unroll
                for (int i = 0; i < 4; ++i) {
                    int r = i * 16 + lr;
                    int kc = (kt * 4 + lc) ^ (r & 7);
                    af[i] = *(const bf16x8*)&xb[r * 64 + kc * 8];
                }
#pragma unroll
                for (int j = 0; j < 8; ++j) {
                    int nt = w * 8 + j;
                    bf16x8 bfv = *(const bf16x8*)&wbase[(size_t)(nt * 2 + kt) * 512 + lane * 8];
#pragma unroll
                    for (int i = 0; i < 4; ++i)
                        acc[i][j] = __builtin_amdgcn_mfma_f32_16x16x32_bf16(af[i], bfv, acc[i][j], 0, 0, 0);
                }
            }
            bool isH = (w < 2);
            const float* bias = isH ? vg_b1 + n * 256 : vg_skipb + n * 256;
            __bf16* dst = isH ? hb : skb;
            int colbase = (w & 1) * 128;
#pragma unroll
            for (int j = 0; j < 8; ++j) {
                int col = colbase + j * 16 + lr;
                float bv = bias[col];
#pragma unroll
                for (int i = 0; i < 4; ++i)
#pragma unroll
                    for (int q = 0; q < 4; ++q) {
                        int row = i * 16 + lc * 4 + q;
                        float x = acc[i][j][q] + bv;
                        if (isH) x = x > 0.f ? x : (__expf(x) - 1.f);
                        dst[row * 256 + (((col >> 3) ^ (row & 7)) << 3) + (col & 7)] = (__bf16)x;
                    }
            }
        }
        __syncthreads();

        // ---- GEMM2: hb @ Wf_n (a: cols 0..255, gate: 256..511) + combine ----
        {
            f32x4 aA[4][4] = {}, aG[4][4] = {};
            const __bf16* wbase = Wfp + (size_t)n * 131072;
#pragma unroll
            for (int kt = 0; kt < 8; ++kt) {
                bf16x8 af[4];
#pragma unroll
                for (int i = 0; i < 4; ++i) {
                    int r = i * 16 + lr;
                    int kc = (kt * 4 + lc) ^ (r & 7);
                    af[i] = *(const bf16x8*)&hb[r * 256 + kc * 8];
                }
#pragma unroll
                for (int j = 0; j < 4; ++j) {
                    int nta = w * 4 + j, ntg = nta + 16;
                    bf16x8 ba = *(const bf16x8*)&wbase[(size_t)(nta * 8 + kt) * 512 + lane * 8];
                    bf16x8 bg = *(const bf16x8*)&wbase[(size_t)(ntg * 8 + kt) * 512 + lane * 8];
#pragma unroll
                    for (int i = 0; i < 4; ++i) {
                        aA[i][j] = __builtin_amdgcn_mfma_f32_16x16x32_bf16(af[i], ba, aA[i][j], 0, 0, 0);
                        aG[i][j] = __builtin_amdgcn_mfma_f32_16x16x32_bf16(af[i], bg, aG[i][j], 0, 0, 0);
                    }
                }
            }
            const float* bW = bWf + n * 512;
#pragma unroll
            for (int j = 0; j < 4; ++j) {
                int col = w * 64 + j * 16 + lr;
                float ba_ = bW[col], bg_ = bW[col + 256];
#pragma unroll
                for (int i = 0; i < 4; ++i)
#pragma unroll
                    for (int q = 0; q < 4; ++q) {
                        int row = i * 16 + lc * 4 + q;
                        float sk = (float)skb[row * 256 + (((col >> 3) ^ (row & 7)) << 3) + (col & 7)];
                        float av = aA[i][j][q] + ba_;
                        float gv = aG[i][j][q] + bg_;
                        aA[i][j][q] = sk + av * (1.f / (1.f + __expf(-gv)));
                    }
            }
#pragma unroll
            for (int i = 0; i < 4; ++i)
#pragma unroll
                for (int q = 0; q < 4; ++q) {
                    float s = 0.f, ss = 0.f;
#pragma unroll
                    for (int j = 0; j < 4; ++j) { float v = aA[i][j][q]; s += v; ss += v * v; }
                    s += __shfl_xor(s, 1); ss += __shfl_xor(ss, 1);
                    s += __shfl_xor(s, 2); ss += __shfl_xor(ss, 2);
                    s += __shfl_xor(s, 4); ss += __shfl_xor(ss, 4);
                    s += __shfl_xor(s, 8); ss += __shfl_xor(ss, 8);
                    if (lr == 0) {
                        int row = i * 16 + lc * 4 + q;
                        red[row][w][0] = s; red[row][w][1] = ss;
                    }
                }
            __syncthreads();
            const float* gma = vg_gamma + n * 256;
            const float* bta = vg_beta + n * 256;
            float gmj[4], btj[4];
#pragma unroll
            for (int j = 0; j < 4; ++j) {
                int col = w * 64 + j * 16 + lr;
                gmj[j] = gma[col]; btj[j] = bta[col];
            }
#pragma unroll
            for (int i = 0; i < 4; ++i)
#pragma unroll
                for (int q = 0; q < 4; ++q) {
                    int row = i * 16 + lc * 4 + q;
                    float s  = red[row][0][0] + red[row][1][0] + red[row][2][0] + red[row][3][0];
                    float ss = red[row][0][1] + red[row][1][1] + red[row][2][1] + red[row][3][1];
                    float mean = s * (1.f / 256.f);
                    float var  = ss * (1.f / 256.f) - mean * mean;
                    float rstd = rsqrtf(var + 1e-5f);
                    float wv = wls[row * 16 + n];
#pragma unroll
                    for (int j = 0; j < 4; ++j) {
                        int col = w * 64 + j * 16 + lr;
                        float pv = (aA[i][j][q] - mean) * rstd * gmj[j] + btj[j];
                        selL[row * SELP + col] += wv * pv;
                    }
                }
        }
    }

    // ======== output GRN (identity skip = selL) ========
    __syncthreads();
    for (int idx = tid; idx < 64 * 256; idx += 256) {
        int row = idx >> 8, col = idx & 255;
        hb[row * 256 + (((col >> 3) ^ (row & 7)) << 3) + (col & 7)] = (__bf16)selL[row * SELP + col];
    }
    __syncthreads();

    // GEMM1': h5 = elu(selb @ ogW1 + og_b1) -> skb
    {
        f32x4 acc[4][4] = {};
#pragma unroll
        for (int kt = 0; kt < 8; ++kt) {
            bf16x8 af[4];
#pragma unroll
            for (int i = 0; i < 4; ++i) {
                int r = i * 16 + lr;
                int kc = (kt * 4 + lc) ^ (r & 7);
                af[i] = *(const bf16x8*)&hb[r * 256 + kc * 8];
            }
#pragma unroll
            for (int j = 0; j < 4; ++j) {
                int nt = w * 4 + j;
                bf16x8 bfv = *(const bf16x8*)&ogW1p[(size_t)(nt * 8 + kt) * 512 + lane * 8];
#pragma unroll
                for (int i = 0; i < 4; ++i)
                    acc[i][j] = __builtin_amdgcn_mfma_f32_16x16x32_bf16(af[i], bfv, acc[i][j], 0, 0, 0);
            }
        }
#pragma unroll
        for (int j = 0; j < 4; ++j) {
            int col = w * 64 + j * 16 + lr;
            float bv = og_b1[col];
#pragma unroll
            for (int i = 0; i < 4; ++i)
#pragma unroll
                for (int q = 0; q < 4; ++q) {
                    int row = i * 16 + lc * 4 + q;
                    float x = acc[i][j][q] + bv;
                    x = x > 0.f ? x : (__expf(x) - 1.f);
                    skb[row * 256 + (((col >> 3) ^ (row & 7)) << 3) + (col & 7)] = (__bf16)x;
                }
        }
    }
    __syncthreads();

    // GEMM2': g5 = h5 @ ogWf + ogbWf; out = LN(selL + a*sig(g))
    {
        f32x4 aA[4][4] = {}, aG[4][4] = {};
#pragma unroll
        for (int kt = 0; kt < 8; ++kt) {
            bf16x8 af[4];
#pragma unroll
            for (int i = 0; i < 4; ++i) {
                int r = i * 16 + lr;
                int kc = (kt * 4 + lc) ^ (r & 7);
                af[i] = *(const bf16x8*)&skb[r * 256 + kc * 8];
            }
#pragma unroll
            for (int j = 0; j < 4; ++j) {
                int nta = w * 4 + j, ntg = nta + 16;
                bf16x8 ba = *(const bf16x8*)&ogWfp[(size_t)(nta * 8 + kt) * 512 + lane * 8];
                bf16x8 bg = *(const bf16x8*)&ogWfp[(size_t)(ntg * 8 + kt) * 512 + lane * 8];
#pragma unroll
                for (int i = 0; i < 4; ++i) {
                    aA[i][j] = __builtin_amdgcn_mfma_f32_16x16x32_bf16(af[i], ba, aA[i][j], 0, 0, 0);
                    aG[i][j] = __builtin_amdgcn_mfma_f32_16x16x32_bf16(af[i], bg, aG[i][j], 0, 0, 0);
                }
            }
        }
#pragma unroll
        for (int j = 0; j < 4; ++j) {
            int col = w * 64 + j * 16 + lr;
            float ba_ = ogbWf[col], bg_ = ogbWf[col + 256];
#pragma unroll
            for (int i = 0; i < 4; ++i)
#pragma unroll
                for (int q = 0; q < 4; ++q) {
                    int row = i * 16 + lc * 4 + q;
                    float sk = selL[row * SELP + col];
                    float av = aA[i][j][q] + ba_;
                    float gv = aG[i][j][q] + bg_;
                    aA[i][j][q] = sk + av * (1.f / (1.f + __expf(-gv)));
                }
        }
#pragma unroll
        for (int i = 0; i < 4; ++i)
#pragma unroll
            for (int q = 0; q < 4; ++q) {
                float s = 0.f, ss = 0.f;
#pragma unroll
                for (int j = 0; j < 4; ++j) { float v = aA[i][j][q]; s += v; ss += v * v; }
                s += __shfl_xor(s, 1); ss += __shfl_xor(ss, 1);
                s += __shfl_xor(s, 2); ss += __shfl_xor(ss, 2);
                s += __shfl_xor(s, 4); ss += __shfl_xor(ss, 4);
                s += __shfl_xor(s, 8); ss += __shfl_xor(ss, 8);
                if (lr == 0) {
                    int row = i * 16 + lc * 4 + q;
                    red[row][w][0] = s; red[row][w][1] = ss;
                }
            }
        __syncthreads();
        float gmj[4], btj[4];
#pragma unroll
        for (int j = 0; j < 4; ++j) {
            int col = w * 64 + j * 16 + lr;
            gmj[j] = og_gamma[col]; btj[j] = og_beta[col];
        }
#pragma unroll
        for (int i = 0; i < 4; ++i)
#pragma unroll
            for (int q = 0; q < 4; ++q) {
                int row = i * 16 + lc * 4 + q;
                float s  = red[row][0][0] + red[row][1][0] + red[row][2][0] + red[row][3][0];
                float ss = red[row][0][1] + red[row][1][1] + red[row][2][1] + red[row][3][1];
                float mean = s * (1.f / 256.f);
                float var  = ss * (1.f / 256.f) - mean * mean;
                float rstd = rsqrtf(var + 1e-5f);
#pragma unroll
                for (int j = 0; j < 4; ++j) {
                    int col = w * 64 + j * 16 + lr;
                    out[(row0 + row) * 256 + col] = (aA[i][j][q] - mean) * rstd * gmj[j] + btj[j];
                }
            }
    }
}

// ---------------------------------------------------------------------------
extern "C" void kernel_launch(void* const* d_in, const int* in_sizes, int n_in,
                              void* d_out, int out_size, void* d_ws, size_t ws_size,
                              hipStream_t stream)
{
    const float* vars     = (const float*)d_in[0];
    const float* ctx      = (const float*)d_in[1];
    const float* fg_W1    = (const float*)d_in[2];
    const float* fg_b1    = (const float*)d_in[3];
    const float* fg_Wc    = (const float*)d_in[4];
    const float* fg_W2    = (const float*)d_in[5];
    const float* fg_b2    = (const float*)d_in[6];
    const float* fg_Wg    = (const float*)d_in[7];
    const float* fg_bg    = (const float*)d_in[8];
    const float* fg_skipW = (const float*)d_in[9];
    const float* fg_skipb = (const float*)d_in[10];
    const float* fg_gamma = (const float*)d_in[11];
    const float* fg_beta  = (const float*)d_in[12];
    const float* vg_W1    = (const float*)d_in[13];
    const float* vg_b1    = (const float*)d_in[14];
    const float* vg_W2    = (const float*)d_in[15];
    const float* vg_b2    = (const float*)d_in[16];
    const float* vg_Wg    = (const float*)d_in[17];
    const float* vg_bg    = (const float*)d_in[18];
    const float* vg_skipW = (const float*)d_in[19];
    const float* vg_skipb = (const float*)d_in[20];
    const float* vg_gamma = (const float*)d_in[21];
    const float* vg_beta  = (const float*)d_in[22];
    const float* og_W1    = (const float*)d_in[23];
    const float* og_b1    = (const float*)d_in[24];
    const float* og_W2    = (const float*)d_in[25];
    const float* og_b2    = (const float*)d_in[26];
    const float* og_Wg    = (const float*)d_in[27];
    const float* og_bg    = (const float*)d_in[28];
    const float* og_gamma = (const float*)d_in[29];
    const float* og_beta  = (const float*)d_in[30];

    float* out = (float*)d_out;
    float* wsm = out + (long)BT * ODIM;

    // ---- workspace ----
    char* W = (char*)d_ws;
    size_t o = 0;
    auto alloc = [&](size_t b) { void* p = W + o; o += (b + 255) & ~(size_t)255; return p; };
    __bf16* WgT    = (__bf16*)alloc((size_t)17 * 512 * 256 * 2);   // [z][512][256]
    __bf16* Wfb    = (__bf16*)alloc((size_t)17 * 256 * 512 * 2);   // [z][256][512]
    __bf16* Wfp    = (__bf16*)alloc((size_t)16 * 131072 * 2);      // frag-packed vg Wf
    __bf16* ogWfp  = (__bf16*)alloc((size_t)131072 * 2);
    __bf16* ogW1p  = (__bf16*)alloc((size_t)65536 * 2);
    __bf16* W1Sp   = (__bf16*)alloc((size_t)16 * 32768 * 2);
    __bf16* Btk1   = (__bf16*)alloc((size_t)384 * 1024 * 2);
    float*  bias2  = (float*)alloc((size_t)128 * 4);
    float*  bWf    = (float*)alloc((size_t)16 * 512 * 4);
    float*  ogbWf  = (float*)alloc((size_t)512 * 4);
    float*  fgWf   = (float*)alloc((size_t)256 * 32 * 4);
    float*  fgbf   = (float*)alloc((size_t)32 * 4);
    float*  ctxh   = (float*)alloc((size_t)64 * 256 * 4);
    __bf16* h1     = (__bf16*)alloc((size_t)BT * 256 * 2);
    __bf16* skip16 = (__bf16*)alloc((size_t)BT * 128 * 2);

    dim3 blk(256);
    const int NOSPLIT = 1 << 30;

    // ---- setup ----
    transpose_cast<<<dim3(128, 16), blk, 0, stream>>>(vg_Wg, WgT, 256, 512, 131072, 131072);
    transpose_cast<<<dim3(128, 1), blk, 0, stream>>>(og_Wg, WgT + (size_t)16 * 131072, 256, 512, 0, 0);
    // Wf = W2 @ Wg  (MFMA, f32 A)
    gemm_mfma<1><<<dim3(4, 2, 16), blk, 0, stream>>>(vg_W2, WgT, nullptr, nullptr,
                                                     Wfb, nullptr, 256, 256, 256, 512, 0,
                                                     nullptr, 0, NOSPLIT, 65536, 131072, 131072);
    gemm_mfma<1><<<dim3(4, 2, 1), blk, 0, stream>>>(og_W2, WgT + (size_t)16 * 131072, nullptr, nullptr,
                                                    Wfb + (size_t)16 * 131072, nullptr, 256, 256, 256, 512, 0,
                                                    nullptr, 0, NOSPLIT, 0, 0, 0);
    bfuse<<<17, 512, 0, stream>>>(vg_b2, vg_Wg, vg_bg, og_b2, og_Wg, og_bg, bWf, ogbWf);
    fgfuse<<<32, 256, 0, stream>>>(fg_W2, fg_Wg, fg_b2, fg_bg, fgWf, fgbf);
    transpose_cast<<<dim3(256, 1), blk, 0, stream>>>(fg_W1, Btk1, 1024, 256, 0, 0);
    pad_skip<<<128, blk, 0, stream>>>(fg_skipW, fg_skipb, Btk1, bias2);
    frag_pack_w1s<<<dim3(64, 16), 64, 0, stream>>>(vg_W1, vg_skipW, W1Sp);
    frag_pack_bf16<<<dim3(256, 16), 64, 0, stream>>>(Wfb, Wfp, 256, 512, 131072, 131072);
    frag_pack_bf16<<<dim3(256, 1), 64, 0, stream>>>(Wfb + (size_t)16 * 131072, ogWfp, 256, 512, 0, 0);
    frag_pack_f32<<<dim3(128, 1), 64, 0, stream>>>(og_W1, ogW1p, 256, 256);
    gemm_f32z<<<dim3(4, 1), blk, 0, stream>>>(ctx, fg_Wc, ctxh, 64, CDIM, HDIM, HDIM);

    // ---- flatten GRN: h1 (cols 0..255, elu+ctx) | skip16 (cols 256..383) ----
    gemm_mfma<1><<<dim3(3, 128), blk, 0, stream>>>(vars, Btk1, fg_b1, bias2,
                                                   h1, skip16, FDIM, FDIM, FDIM, HDIM, 128,
                                                   ctxh, 1, 256, 0, 0, 0);
    k2_logits<<<BT / 4, blk, 0, stream>>>(h1, skip16, fgWf, fgbf, fg_gamma, fg_beta, wsm);

    // ---- everything else in one kernel ----
    vsn_mega<<<256, blk, 0, stream>>>(vars, wsm, W1Sp, Wfp,
                                      vg_b1, vg_skipb, bWf, vg_gamma, vg_beta,
                                      ogW1p, ogWfp, og_b1, ogbWf, og_gamma, og_beta,
                                      out);
}